// Round 2
// baseline (2013.566 us; speedup 1.0000x reference)
//
#include <hip/hip_runtime.h>

#define BATCH 16
#define CH 32
#define DC 3
#define SS 128
#define HH 255
#define M1 12
#define M2 12
#define KY24 (2*M1)
#define NPIX (HH*HH)
#define NROWS (BATCH*CH*HH)

// ---------------- twiddles + identity BN slot ----------------
__global__ void k_tw(float* __restrict__ twc, float* __restrict__ tws,
                     float* __restrict__ bnp0){
  int i = threadIdx.x;
  if (i < HH){
    float a = 6.2831853071795864769f / (float)HH * (float)i;
    twc[i] = cosf(a);
    tws[i] = sinf(a);
  }
  if (i < CH){ bnp0[i] = 1.f; bnp0[CH+i] = 0.f; }
}

// ---------------- mirror + fc0 lift: x(16,3,128,128) -> h(16,32,255,255) ----
__global__ void __launch_bounds__(256) k_fc0(
    const float* __restrict__ x, const float* __restrict__ w,
    const float* __restrict__ bias, float* __restrict__ h){
  int y = blockIdx.x, b = blockIdx.y, xx = threadIdx.x;
  if (xx >= HH) return;
  int iy = (y  >= SS-1) ? y  - (SS-1) : (SS-1) - y;
  int ix = (xx >= SS-1) ? xx - (SS-1) : (SS-1) - xx;
  float sgn = ((y >= SS-1) == (xx >= SS-1)) ? 1.f : -1.f;
  float v0 = sgn * x[((b*DC + 0)*SS + iy)*SS + ix];
  float v1 = sgn * x[((b*DC + 1)*SS + iy)*SS + ix];
  float v2 = sgn * x[((b*DC + 2)*SS + iy)*SS + ix];
  int base = (b*CH*HH + y)*HH + xx;
  for (int d=0; d<CH; d++){
    h[base + d*NPIX] = bias[d] + v0*w[d] + v1*w[CH+d] + v2*w[2*CH+d];
  }
}

// ---------------- forward DFT along W (BN+ReLU applied on load) ------------
__global__ void __launch_bounds__(256) k_dftw(
    const float* __restrict__ h, float* __restrict__ R,
    const float* __restrict__ twc, const float* __restrict__ tws,
    const float* __restrict__ bnp, int relu){
  __shared__ float rows[16][HH];
  __shared__ float lc[HH], ls[HH];
  __shared__ float rsc[16], rsh[16];
  int t = threadIdx.x;
  int base = blockIdx.x * (16*HH);
  if (t < 16){
    int row = blockIdx.x*16 + t;
    int c = (row / HH) & (CH-1);
    rsc[t] = bnp[c]; rsh[t] = bnp[CH+c];
  }
  for (int i=t; i<HH; i+=256){ lc[i]=twc[i]; ls[i]=tws[i]; }
  __syncthreads();
  for (int i=t; i<16*HH; i+=256){
    int r = i/HH;
    float v = h[base + i]*rsc[r] + rsh[r];
    if (relu) v = fmaxf(v, 0.f);
    ((float*)rows)[i] = v;
  }
  __syncthreads();
  int r = t >> 4, kx = t & 15;
  if (kx < M2){
    float ar=0.f, ai=0.f;
    int idx = 0;
    for (int xx=0; xx<HH; xx++){
      float v = rows[r][xx];
      ar += v*lc[idx];
      ai -= v*ls[idx];
      idx += kx; if (idx >= HH) idx -= HH;
    }
    int row = blockIdx.x*16 + r;
    R[(row*M2 + kx)*2 + 0] = ar;
    R[(row*M2 + kx)*2 + 1] = ai;
  }
}

// ---------------- forward DFT along H: R -> Xf[bc][ky24][kx12], *1/255 -----
__global__ void __launch_bounds__(320) k_dfth(
    const float* __restrict__ R, float* __restrict__ Xf,
    const float* __restrict__ twc, const float* __restrict__ tws){
  __shared__ float lr[HH][M2][2];
  __shared__ float lc[HH], ls[HH];
  int t = threadIdx.x, bc = blockIdx.x;
  const float* src = R + bc*(HH*M2*2);
  for (int i=t; i<HH*M2*2; i+=320) ((float*)lr)[i] = src[i];
  for (int i=t; i<HH; i+=320){ lc[i]=twc[i]; ls[i]=tws[i]; }
  __syncthreads();
  if (t < KY24*M2){
    int ky = t / M2, kx = t - (t/M2)*M2;
    int freq = (ky < M1) ? ky : (HH - KY24 + ky);  // 0..11 or 243..254
    float ar=0.f, ai=0.f;
    int idx = 0;
    for (int y=0; y<HH; y++){
      float c = lc[idx], s = ls[idx];
      float rr = lr[y][kx][0], ri = lr[y][kx][1];
      ar += rr*c + ri*s;   // * e^{-i theta}
      ai += ri*c - rr*s;
      idx += freq; if (idx >= HH) idx -= HH;
    }
    const float inv = 1.0f/255.0f;
    int o = (bc*KY24 + ky)*(M2*2) + kx*2;
    Xf[o]   = ar*inv;
    Xf[o+1] = ai*inv;
  }
}

// ---------------- per-mode 32x32 complex channel mix -----------------------
// w layout per layer: [2][i][o][m1][m2][2]
__global__ void __launch_bounds__(384) k_mix(
    const float* __restrict__ Xf, const float* __restrict__ w,
    float* __restrict__ Y){
  int m2 = blockIdx.x, blk = blockIdx.y, b = blockIdx.z;
  int t = threadIdx.x;
  __shared__ float lx[CH][M1][2];
  for (int i=t; i<CH*M1*2; i+=384){
    int ii = i/(M1*2), rem = i - ii*(M1*2);
    int m1 = rem>>1, comp = rem&1;
    lx[ii][m1][comp] = Xf[((b*CH+ii)*KY24 + blk*M1 + m1)*(M2*2) + m2*2 + comp];
  }
  __syncthreads();
  int m1 = t >> 5, o = t & 31;
  float ar=0.f, ai=0.f;
  const float* wp = w + ((blk*CH*CH + o)*M1 + m1)*(M2*2) + m2*2;
  const int istride = CH*M1*M2*2;
  for (int i=0;i<CH;i++){
    float xr = lx[i][m1][0], xi = lx[i][m1][1];
    float wr = wp[0], wi = wp[1];
    ar += xr*wr - xi*wi;
    ai += xr*wi + xi*wr;
    wp += istride;
  }
  int oidx = ((b*CH+o)*KY24 + blk*M1 + m1)*(M2*2) + m2*2;
  Y[oidx]   = ar;
  Y[oidx+1] = ai;
}

// ---------------- inverse along H: Y modes -> G[bo][y][kx] -----------------
// folds 1/255 (ortho) and the x2 Hermitian pairing factor for kx>=1
__global__ void __launch_bounds__(256) k_idfth(
    const float* __restrict__ Y, float* __restrict__ G,
    const float* __restrict__ twc, const float* __restrict__ tws){
  __shared__ float ly[KY24][M2][2];
  __shared__ float lc[HH], ls[HH];
  int t = threadIdx.x, bo = blockIdx.x;
  const float* src = Y + bo*(KY24*M2*2);
  for (int i=t; i<KY24*M2*2; i+=256) ((float*)ly)[i] = src[i];
  for (int i=t; i<HH; i+=256){ lc[i]=twc[i]; ls[i]=tws[i]; }
  __syncthreads();
  const float inv = 1.0f/255.0f;
  for (int p=t; p<HH*M2; p+=256){
    int y = p/M2, kx = p - (p/M2)*M2;
    float ar=0.f, ai=0.f;
    int idx = 0;
    for (int j=0;j<M1;j++){           // freq = j
      float c=lc[idx], s=ls[idx];
      float yr=ly[j][kx][0], yi=ly[j][kx][1];
      ar += yr*c - yi*s;              // * e^{+i theta}
      ai += yr*s + yi*c;
      idx += y; if (idx>=HH) idx -= HH;
    }
    idx = (243*y) % HH;               // freq = 243 at j=12
    for (int j=M1;j<KY24;j++){
      float c=lc[idx], s=ls[idx];
      float yr=ly[j][kx][0], yi=ly[j][kx][1];
      ar += yr*c - yi*s;
      ai += yr*s + yi*c;
      idx += y; if (idx>=HH) idx -= HH;
    }
    float f = (kx==0) ? inv : 2.0f*inv;
    int o = (bo*HH + y)*(M2*2) + kx*2;
    G[o]   = ar*f;
    G[o+1] = ai*f;
  }
}

// ------- fused: BN-on-load + inverse along W + 1x1 conv + BN partials ------
// writes the RAW x1+x2 field IN PLACE (row-local), stats taken on raw values
__global__ void __launch_bounds__(256) k_fuse(
    const float* __restrict__ h, const float* __restrict__ G,
    const float* __restrict__ cw, const float* __restrict__ cb,
    float* __restrict__ tout, float* __restrict__ partials,
    const float* __restrict__ twc, const float* __restrict__ tws,
    const float* __restrict__ bnp, int relu){
  __shared__ float lh[CH][HH];
  __shared__ float lgr[CH][M2], lgi[CH][M2];
  __shared__ float lc[HH], ls[HH];
  __shared__ float lsc[CH], lsh[CH];
  __shared__ float red[4][CH][2];
  int y = blockIdx.x, b = blockIdx.y, t = threadIdx.x;
  int hbase = (b*CH*HH + y)*HH;
  if (t < CH){ lsc[t] = bnp[t]; lsh[t] = bnp[CH+t]; }
  for (int i=t; i<CH*HH; i+=256){
    int c = i/HH, xx = i - c*HH;
    lh[c][xx] = h[hbase + c*NPIX + xx];
  }
  for (int i=t; i<CH*M2; i+=256){
    int o = i/M2, kx = i - (i/M2)*M2;
    int gi = ((b*CH+o)*HH + y)*(M2*2) + kx*2;
    lgr[o][kx] = G[gi];
    lgi[o][kx] = G[gi+1];
  }
  for (int i=t; i<HH; i+=256){ lc[i]=twc[i]; ls[i]=tws[i]; }
  __syncthreads();
  int xx = t;
  float hl[CH];
  if (xx < HH){
    for (int c=0;c<CH;c++){
      float v = lh[c][xx]*lsc[c] + lsh[c];
      hl[c] = relu ? fmaxf(v, 0.f) : v;
    }
  }
  int wave = t >> 6;
  for (int o=0;o<CH;o++){
    float acc = 0.f;
    if (xx < HH){
      acc = cb[o];
      for (int c=0;c<CH;c++) acc += hl[c]*cw[o*CH + c];
      float sp = lgr[o][0];             // Re(G0); imag of bin 0 ignored (C2R)
      int id = xx;
      for (int kx=1;kx<M2;kx++){
        sp += lgr[o][kx]*lc[id] - lgi[o][kx]*ls[id];
        id += xx; if (id >= HH) id -= HH;
      }
      acc += sp;
      tout[hbase + o*NPIX + xx] = acc;
    }
    float a1 = acc, a2 = acc*acc;       // all 256 threads join the shuffle
    for (int off=32; off>0; off>>=1){
      a1 += __shfl_xor(a1, off, 64);
      a2 += __shfl_xor(a2, off, 64);
    }
    if ((t & 63) == 0){ red[wave][o][0] = a1; red[wave][o][1] = a2; }
  }
  __syncthreads();
  if (t < CH*2){
    int o = t >> 1, st = t & 1;
    float s = red[0][o][st] + red[1][o][st] + red[2][o][st] + red[3][o][st];
    partials[(o*2+st)*(BATCH*HH) + b*HH + y] = s;
  }
}

// ---------------- deterministic stats reduce -> scale/shift ----------------
__global__ void k_stats(const float* __restrict__ partials,
                        const float* __restrict__ g, const float* __restrict__ bb,
                        float* __restrict__ bnp){
  __shared__ float acc[64];
  int t = threadIdx.x;
  float s = 0.f;
  const float* p = partials + t*(BATCH*HH);
  for (int i=0;i<BATCH*HH;i++) s += p[i];
  acc[t] = s;
  __syncthreads();
  if (t < CH){
    const float N = (float)BATCH * (float)NPIX;
    float mean = acc[2*t] / N;
    float var  = acc[2*t+1] / N - mean*mean;
    float inv  = rsqrtf(var + 1e-5f);
    float sc   = g[t]*inv;
    bnp[t]      = sc;
    bnp[CH + t] = bb[t] - mean*sc;
  }
}

// ------- final: BN(l3, no relu) + fc1 + relu + fc2, quadrant only ----------
__global__ void __launch_bounds__(128) k_final(
    const float* __restrict__ tb, const float* __restrict__ bnp,
    const float* __restrict__ w1, const float* __restrict__ b1,
    const float* __restrict__ w2, const float* __restrict__ b2,
    float* __restrict__ out){
  int yq = blockIdx.x, b = blockIdx.y, t = threadIdx.x;
  int y = (SS-1) + yq, xx = (SS-1) + t;
  float v[CH];
  int base = (b*CH*HH + y)*HH + xx;
  for (int c=0;c<CH;c++)
    v[c] = tb[base + c*NPIX]*bnp[c] + bnp[CH+c];
  float o2 = b2[0];
  for (int d=0; d<128; d++){
    float u = b1[d];
    for (int c=0;c<CH;c++) u += v[c]*w1[c*128 + d];
    o2 += fmaxf(u, 0.f)*w2[d];
  }
  int ob = (b*DC*SS + yq)*SS + t;
  out[ob]           = o2;
  out[ob +   SS*SS] = o2;
  out[ob + 2*SS*SS] = o2;
}

extern "C" void kernel_launch(void* const* d_in, const int* in_sizes, int n_in,
                              void* d_out, int out_size, void* d_ws, size_t ws_size,
                              hipStream_t stream) {
  (void)in_sizes; (void)n_in; (void)out_size; (void)ws_size;
  const float* x      = (const float*)d_in[0];
  const float* fc0_w  = (const float*)d_in[1];
  const float* fc0_b  = (const float*)d_in[2];
  const float* spec_w = (const float*)d_in[3];
  const float* conv_w = (const float*)d_in[4];
  const float* conv_b = (const float*)d_in[5];
  const float* bn_g   = (const float*)d_in[6];
  const float* bn_b   = (const float*)d_in[7];
  const float* fc1_w  = (const float*)d_in[8];
  const float* fc1_b  = (const float*)d_in[9];
  const float* fc2_w  = (const float*)d_in[10];
  const float* fc2_b  = (const float*)d_in[11];
  float* out = (float*)d_out;
  float* ws  = (float*)d_ws;

  // workspace layout: 37,278,014 floats ~= 142.2 MiB total
  const size_t NB = (size_t)BATCH*CH*NPIX;             // 33,292,800 (127 MiB)
  float* field = ws;
  float* Rbuf  = field + NB;                           // 3,133,440 (also G)
  float* Xf    = Rbuf + (size_t)NROWS*M2*2;            // 294,912
  float* Yb    = Xf   + (size_t)BATCH*CH*KY24*M2*2;    // 294,912
  float* parts = Yb   + (size_t)BATCH*CH*KY24*M2*2;    // 261,120
  float* bnp   = parts + (size_t)64*BATCH*HH;          // 5 slots x 64
  float* twc   = bnp + 5*64;
  float* tws   = twc + HH;

  k_tw<<<1, 256, 0, stream>>>(twc, tws, bnp);          // slot 0 = identity
  k_fc0<<<dim3(HH, BATCH), 256, 0, stream>>>(x, fc0_w, fc0_b, field);

  const size_t wstride = (size_t)2*CH*CH*M1*M2*2;      // per-layer spec_w elems
  for (int l=0; l<4; l++){
    const float* bnin = bnp + (size_t)l*64;            // BN of layer l-1 (or id)
    int relu = (l >= 1);                               // ReLU after layers 0..2
    k_dftw <<<NROWS/16, 256, 0, stream>>>(field, Rbuf, twc, tws, bnin, relu);
    k_dfth <<<BATCH*CH, 320, 0, stream>>>(Rbuf, Xf, twc, tws);
    k_mix  <<<dim3(M2, 2, BATCH), 384, 0, stream>>>(Xf, spec_w + (size_t)l*wstride, Yb);
    k_idfth<<<BATCH*CH, 256, 0, stream>>>(Yb, Rbuf, twc, tws);
    k_fuse <<<dim3(HH, BATCH), 256, 0, stream>>>(field, Rbuf, conv_w + l*CH*CH,
                                                 conv_b + l*CH, field, parts,
                                                 twc, tws, bnin, relu);
    k_stats<<<1, 64, 0, stream>>>(parts, bn_g + l*CH, bn_b + l*CH,
                                  bnp + (size_t)(l+1)*64);
  }
  k_final<<<dim3(SS, BATCH), 128, 0, stream>>>(field, bnp + 4*64, fc1_w, fc1_b,
                                               fc2_w, fc2_b, out);
}

// Round 3
// 1209.305 us; speedup vs baseline: 1.6651x; 1.6651x over previous
//
#include <hip/hip_runtime.h>

#define BATCH 16
#define CH 32
#define DC 3
#define SS 128
#define HH 255
#define M1 12
#define M2 12
#define KY24 (2*M1)
#define NPIX (HH*HH)
#define NROWS (BATCH*CH*HH)
#define TWOPI_N 0.02463994238463573f   // 2*pi/255

// ---------------- mirror + fc0 lift (+ identity BN slot init) --------------
__global__ void __launch_bounds__(256) k_fc0(
    const float* __restrict__ x, const float* __restrict__ w,
    const float* __restrict__ bias, float* __restrict__ h,
    float* __restrict__ bnp0){
  int y = blockIdx.x, b = blockIdx.y, xx = threadIdx.x;
  if (blockIdx.x == 0 && blockIdx.y == 0 && xx < CH){
    bnp0[xx] = 1.f; bnp0[CH+xx] = 0.f;
  }
  if (xx >= HH) return;
  int iy = (y  >= SS-1) ? y  - (SS-1) : (SS-1) - y;
  int ix = (xx >= SS-1) ? xx - (SS-1) : (SS-1) - xx;
  float sgn = ((y >= SS-1) == (xx >= SS-1)) ? 1.f : -1.f;
  float v0 = sgn * x[((b*DC + 0)*SS + iy)*SS + ix];
  float v1 = sgn * x[((b*DC + 1)*SS + iy)*SS + ix];
  float v2 = sgn * x[((b*DC + 2)*SS + iy)*SS + ix];
  int base = (b*CH*HH + y)*HH + xx;
  for (int d=0; d<CH; d++){
    h[base + d*NPIX] = bias[d] + v0*w[d] + v1*w[CH+d] + v2*w[2*CH+d];
  }
}

// ---------------- forward DFT along W (BN+ReLU on load) --------------------
// thread map: kx = t>>4 (slow), r = t&15 -> rows[] reads are broadcast,
// twiddles via per-lane rotation recurrence (no LDS table).
__global__ void __launch_bounds__(256) k_dftw(
    const float* __restrict__ h, float* __restrict__ R,
    const float* __restrict__ bnp, int relu){
  __shared__ float rows[16][HH];
  __shared__ float rsc[16], rsh[16];
  int t = threadIdx.x;
  int base = blockIdx.x * (16*HH);
  if (t < 16){
    int row = blockIdx.x*16 + t;
    int c = (row / HH) & (CH-1);
    rsc[t] = bnp[c]; rsh[t] = bnp[CH+c];
  }
  __syncthreads();
  const float4* h4 = (const float4*)(h + base);
  for (int i=t; i<(16*HH)/4; i+=256){          // 1020 float4s
    float4 v = h4[i];
    int e = i*4;
    float* dst = &((float*)rows)[e];
    float vv[4] = {v.x, v.y, v.z, v.w};
    #pragma unroll
    for (int u=0; u<4; u++){
      int r = (e+u)/HH;
      float z = vv[u]*rsc[r] + rsh[r];
      dst[u] = relu ? fmaxf(z, 0.f) : z;
    }
  }
  __syncthreads();
  int kx = t >> 4, r = t & 15;
  if (kx < M2){
    float ang = TWOPI_N * (float)kx;
    float c1 = cosf(ang), s1 = sinf(ang);
    float cr = 1.f, sr = 0.f, ar = 0.f, ai = 0.f;
    for (int xx=0; xx<HH; xx++){
      float v = rows[r][xx];
      ar += v*cr;
      ai -= v*sr;
      float cn = cr*c1 - sr*s1;
      sr = sr*c1 + cr*s1;
      cr = cn;
    }
    int row = blockIdx.x*16 + r;
    R[(row*M2 + kx)*2 + 0] = ar;
    R[(row*M2 + kx)*2 + 1] = ai;
  }
}

// ---------------- forward DFT along H: R -> Xf[bc][ky24][kx12], *1/255 -----
__global__ void __launch_bounds__(320) k_dfth(
    const float* __restrict__ R, float* __restrict__ Xf){
  __shared__ float lr[HH][M2][2];
  int t = threadIdx.x, bc = blockIdx.x;
  const float4* src = (const float4*)(R + bc*(HH*M2*2));
  for (int i=t; i<(HH*M2*2)/4; i+=320) ((float4*)lr)[i] = src[i];
  __syncthreads();
  if (t < KY24*M2){
    int ky = t / M2, kx = t - (t/M2)*M2;
    int freq = (ky < M1) ? ky : (HH - KY24 + ky);  // 0..11 or 243..254
    float ang = TWOPI_N * (float)freq;
    float c1 = cosf(ang), s1 = sinf(ang);
    float cr=1.f, sr=0.f, ar=0.f, ai=0.f;
    for (int y=0; y<HH; y++){
      float rr = lr[y][kx][0], ri = lr[y][kx][1];
      ar += rr*cr + ri*sr;   // * e^{-i theta}
      ai += ri*cr - rr*sr;
      float cn = cr*c1 - sr*s1;
      sr = sr*c1 + cr*s1;
      cr = cn;
    }
    const float inv = 1.0f/255.0f;
    int o = (bc*KY24 + ky)*(M2*2) + kx*2;
    Xf[o]   = ar*inv;
    Xf[o+1] = ai*inv;
  }
}

// ---------------- per-mode 32x32 complex channel mix -----------------------
__global__ void __launch_bounds__(384) k_mix(
    const float* __restrict__ Xf, const float* __restrict__ w,
    float* __restrict__ Y){
  int m2 = blockIdx.x, blk = blockIdx.y, b = blockIdx.z;
  int t = threadIdx.x;
  __shared__ float lx[CH][M1][2];
  for (int i=t; i<CH*M1*2; i+=384){
    int ii = i/(M1*2), rem = i - ii*(M1*2);
    int m1 = rem>>1, comp = rem&1;
    lx[ii][m1][comp] = Xf[((b*CH+ii)*KY24 + blk*M1 + m1)*(M2*2) + m2*2 + comp];
  }
  __syncthreads();
  int m1 = t >> 5, o = t & 31;
  float ar=0.f, ai=0.f;
  const float* wp = w + ((blk*CH*CH + o)*M1 + m1)*(M2*2) + m2*2;
  const int istride = CH*M1*M2*2;
  for (int i=0;i<CH;i++){
    float xr = lx[i][m1][0], xi = lx[i][m1][1];
    float wr = wp[0], wi = wp[1];
    ar += xr*wr - xi*wi;
    ai += xr*wi + xi*wr;
    wp += istride;
  }
  int oidx = ((b*CH+o)*KY24 + blk*M1 + m1)*(M2*2) + m2*2;
  Y[oidx]   = ar;
  Y[oidx+1] = ai;
}

// ---------------- inverse along H: Y modes -> G[bo][y][kx] -----------------
// uses T_{-k} = conj(T_k); folds 1/255 and the x2 Hermitian pairing (kx>=1)
__global__ void __launch_bounds__(256) k_idfth(
    const float* __restrict__ Y, float* __restrict__ G){
  __shared__ float ly[KY24][M2][2];
  int t = threadIdx.x, bo = blockIdx.x;
  const float4* src = (const float4*)(Y + bo*(KY24*M2*2));
  for (int i=t; i<(KY24*M2*2)/4; i+=256) ((float4*)ly)[i] = src[i];
  __syncthreads();
  const float inv = 1.0f/255.0f;
  for (int p=t; p<HH*M2; p+=256){
    int y = p/M2, kx = p - (p/M2)*M2;
    float ang = TWOPI_N * (float)y;
    float c1 = cosf(ang), s1 = sinf(ang);
    float ar = ly[0][kx][0], ai = ly[0][kx][1];
    float c = c1, s = s1;
    #pragma unroll
    for (int k=1; k<=11; k++){
      float yr = ly[k][kx][0],     yi = ly[k][kx][1];
      ar += yr*c - yi*s;                 // * T_k
      ai += yr*s + yi*c;
      float zr = ly[24-k][kx][0],  zi = ly[24-k][kx][1];
      ar += zr*c + zi*s;                 // * conj(T_k)
      ai += zi*c - zr*s;
      float cn = c*c1 - s*s1;
      s = s*c1 + c*s1;
      c = cn;
    }
    {
      float zr = ly[12][kx][0], zi = ly[12][kx][1];   // freq -12: conj(T_12)
      ar += zr*c + zi*s;
      ai += zi*c - zr*s;
    }
    float f = (kx==0) ? inv : 2.0f*inv;
    int o = (bo*HH + y)*(M2*2) + kx*2;
    G[o]   = ar*f;
    G[o+1] = ai*f;
  }
}

// ------- fused: BN-on-load + inverse along W + 1x1 conv + BN partials ------
// h -> registers (coalesced), G & cw via scalar loads, twiddles in registers.
__global__ void __launch_bounds__(256) k_fuse(
    const float* __restrict__ h, const float* __restrict__ G,
    const float* __restrict__ cw, const float* __restrict__ cb,
    float* __restrict__ tout, float* __restrict__ partials,
    const float* __restrict__ bnp, int relu){
  __shared__ float ot[CH][HH];        // output tile (for BN partial sums)
  __shared__ float red[CH][8][2];
  __shared__ float lsc[CH], lsh[CH];
  int y = blockIdx.x, b = blockIdx.y, t = threadIdx.x;
  int hbase = (b*CH*HH + y)*HH;
  if (t < CH){ lsc[t] = bnp[t]; lsh[t] = bnp[CH+t]; }
  __syncthreads();
  int xx = t;
  if (xx < HH){
    float hl[CH];
    #pragma unroll
    for (int c=0;c<CH;c++){
      float v = h[hbase + c*NPIX + xx]*lsc[c] + lsh[c];
      hl[c] = relu ? fmaxf(v, 0.f) : v;
    }
    float ck[M2], sk[M2];
    {
      float ang = TWOPI_N * (float)xx;
      ck[1] = cosf(ang); sk[1] = sinf(ang);
      #pragma unroll
      for (int k=2;k<M2;k++){
        ck[k] = ck[k-1]*ck[1] - sk[k-1]*sk[1];
        sk[k] = sk[k-1]*ck[1] + ck[k-1]*sk[1];
      }
    }
    for (int o=0;o<CH;o++){
      int gb = __builtin_amdgcn_readfirstlane(((b*CH+o)*HH + y)*(M2*2));
      const float* gp = G + gb;
      int cwb = __builtin_amdgcn_readfirstlane(o*CH);
      float acc = cb[o];
      #pragma unroll
      for (int c=0;c<CH;c++) acc += hl[c]*cw[cwb + c];
      float sp = gp[0];                  // Re(G0); imag of bin 0 ignored (C2R)
      #pragma unroll
      for (int kx=1;kx<M2;kx++)
        sp += gp[2*kx]*ck[kx] - gp[2*kx+1]*sk[kx];
      acc += sp;
      tout[hbase + o*NPIX + xx] = acc;
      ot[o][xx] = acc;
    }
  }
  __syncthreads();
  // fixed-order per-channel reduction: 8 threads per channel
  int o = t >> 3, j = t & 7;
  float s1v = 0.f, s2v = 0.f;
  for (int k=j; k<HH; k+=8){
    float v = ot[o][k];
    s1v += v; s2v += v*v;
  }
  red[o][j][0] = s1v; red[o][j][1] = s2v;
  __syncthreads();
  if (t < CH*2){
    int oo = t >> 1, st = t & 1;
    float s = 0.f;
    #pragma unroll
    for (int j2=0;j2<8;j2++) s += red[oo][j2][st];
    partials[(oo*2+st)*(BATCH*HH) + b*HH + y] = s;
  }
}

// ---------------- deterministic stats reduce -> scale/shift ----------------
// one block per channel; threads 0-127 reduce sum-row, 128-255 sumsq-row
__global__ void __launch_bounds__(256) k_stats(
    const float* __restrict__ partials,
    const float* __restrict__ g, const float* __restrict__ bb,
    float* __restrict__ bnp){
  __shared__ float acc[256];
  int o = blockIdx.x, t = threadIdx.x;
  int half = t >> 7, j = t & 127;
  const float* p = partials + (size_t)(o*2+half)*(BATCH*HH);
  float s = 0.f;
  for (int k=j; k<BATCH*HH; k+=128) s += p[k];
  acc[t] = s;
  __syncthreads();
  for (int w2=64; w2>0; w2>>=1){
    if (j < w2) acc[t] += acc[t+w2];
    __syncthreads();
  }
  if (t == 0){
    const float N = (float)BATCH * (float)NPIX;
    float mean = acc[0] / N;
    float var  = acc[128] / N - mean*mean;
    float iv = rsqrtf(var + 1e-5f);
    float sc = g[o]*iv;
    bnp[o]      = sc;
    bnp[CH + o] = bb[o] - mean*sc;
  }
}

// ------- final: BN(l3, no relu) + fc1 + relu + fc2, quadrant only ----------
__global__ void __launch_bounds__(128) k_final(
    const float* __restrict__ tb, const float* __restrict__ bnp,
    const float* __restrict__ w1, const float* __restrict__ b1,
    const float* __restrict__ w2, const float* __restrict__ b2,
    float* __restrict__ out){
  int yq = blockIdx.x, b = blockIdx.y, t = threadIdx.x;
  int y = (SS-1) + yq, xx = (SS-1) + t;
  float v[CH];
  int base = (b*CH*HH + y)*HH + xx;
  #pragma unroll
  for (int c=0;c<CH;c++)
    v[c] = tb[base + c*NPIX]*bnp[c] + bnp[CH+c];
  float o2 = b2[0];
  for (int d=0; d<128; d++){
    float u = b1[d];
    #pragma unroll
    for (int c=0;c<CH;c++) u += v[c]*w1[c*128 + d];
    o2 += fmaxf(u, 0.f)*w2[d];
  }
  int ob = (b*DC*SS + yq)*SS + t;
  out[ob]           = o2;
  out[ob +   SS*SS] = o2;
  out[ob + 2*SS*SS] = o2;
}

extern "C" void kernel_launch(void* const* d_in, const int* in_sizes, int n_in,
                              void* d_out, int out_size, void* d_ws, size_t ws_size,
                              hipStream_t stream) {
  (void)in_sizes; (void)n_in; (void)out_size; (void)ws_size;
  const float* x      = (const float*)d_in[0];
  const float* fc0_w  = (const float*)d_in[1];
  const float* fc0_b  = (const float*)d_in[2];
  const float* spec_w = (const float*)d_in[3];
  const float* conv_w = (const float*)d_in[4];
  const float* conv_b = (const float*)d_in[5];
  const float* bn_g   = (const float*)d_in[6];
  const float* bn_b   = (const float*)d_in[7];
  const float* fc1_w  = (const float*)d_in[8];
  const float* fc1_b  = (const float*)d_in[9];
  const float* fc2_w  = (const float*)d_in[10];
  const float* fc2_b  = (const float*)d_in[11];
  float* out = (float*)d_out;
  float* ws  = (float*)d_ws;

  const size_t NB = (size_t)BATCH*CH*NPIX;             // 33,292,800 (127 MiB)
  float* field = ws;
  float* Rbuf  = field + NB;                           // 3,133,440 (also G)
  float* Xf    = Rbuf + (size_t)NROWS*M2*2;            // 294,912
  float* Yb    = Xf   + (size_t)BATCH*CH*KY24*M2*2;    // 294,912
  float* parts = Yb   + (size_t)BATCH*CH*KY24*M2*2;    // 261,120
  float* bnp   = parts + (size_t)64*BATCH*HH;          // 5 slots x 64

  k_fc0<<<dim3(HH, BATCH), 256, 0, stream>>>(x, fc0_w, fc0_b, field, bnp);

  const size_t wstride = (size_t)2*CH*CH*M1*M2*2;      // per-layer spec_w elems
  for (int l=0; l<4; l++){
    const float* bnin = bnp + (size_t)l*64;            // BN of layer l-1 (or id)
    int relu = (l >= 1);                               // ReLU after layers 0..2
    k_dftw <<<NROWS/16, 256, 0, stream>>>(field, Rbuf, bnin, relu);
    k_dfth <<<BATCH*CH, 320, 0, stream>>>(Rbuf, Xf);
    k_mix  <<<dim3(M2, 2, BATCH), 384, 0, stream>>>(Xf, spec_w + (size_t)l*wstride, Yb);
    k_idfth<<<BATCH*CH, 256, 0, stream>>>(Yb, Rbuf);
    k_fuse <<<dim3(HH, BATCH), 256, 0, stream>>>(field, Rbuf, conv_w + l*CH*CH,
                                                 conv_b + l*CH, field, parts,
                                                 bnin, relu);
    k_stats<<<CH, 256, 0, stream>>>(parts, bn_g + l*CH, bn_b + l*CH,
                                    bnp + (size_t)(l+1)*64);
  }
  k_final<<<dim3(SS, BATCH), 128, 0, stream>>>(field, bnp + 4*64, fc1_w, fc1_b,
                                               fc2_w, fc2_b, out);
}

// Round 4
// 925.662 us; speedup vs baseline: 2.1753x; 1.3064x over previous
//
#include <hip/hip_runtime.h>

#define BATCH 16
#define CH 32
#define DC 3
#define SS 128
#define HH 255
#define M1 12
#define M2 12
#define KY24 (2*M1)
#define NPIX (HH*HH)
#define NROWS (BATCH*CH*HH)
#define TWOPI_N 0.02463994238463573f   // 2*pi/255

typedef __attribute__((ext_vector_type(8))) short short8;
typedef __attribute__((ext_vector_type(4))) float f32x4;

__device__ inline unsigned int f2bf_u(float x){
  unsigned int u = __float_as_uint(x);
  return (u + 0x7FFFu + ((u >> 16) & 1u)) >> 16;
}
__device__ inline float bf2f_u(unsigned int s){
  return __uint_as_float(s << 16);
}

// ---------------- mirror + fc0 lift (+ identity BN slot init) --------------
__global__ void __launch_bounds__(256) k_fc0(
    const float* __restrict__ x, const float* __restrict__ w,
    const float* __restrict__ bias, float* __restrict__ h,
    float* __restrict__ bnp0){
  int y = blockIdx.x, b = blockIdx.y, xx = threadIdx.x;
  if (blockIdx.x == 0 && blockIdx.y == 0 && xx < CH){
    bnp0[xx] = 1.f; bnp0[CH+xx] = 0.f;
  }
  if (xx >= HH) return;
  int iy = (y  >= SS-1) ? y  - (SS-1) : (SS-1) - y;
  int ix = (xx >= SS-1) ? xx - (SS-1) : (SS-1) - xx;
  float sgn = ((y >= SS-1) == (xx >= SS-1)) ? 1.f : -1.f;
  float v0 = sgn * x[((b*DC + 0)*SS + iy)*SS + ix];
  float v1 = sgn * x[((b*DC + 1)*SS + iy)*SS + ix];
  float v2 = sgn * x[((b*DC + 2)*SS + iy)*SS + ix];
  int base = (b*CH*HH + y)*HH + xx;
  for (int d=0; d<CH; d++){
    h[base + d*NPIX] = bias[d] + v0*w[d] + v1*w[CH+d] + v2*w[2*CH+d];
  }
}

// ------- DFT weight fragments: W[k][col] in exact B-fragment order ---------
// col = 2m   -> cos(2*pi*k*m/255);  col = 2m+1 -> -sin(2*pi*k*m/255)
// cols 24..31 zero; k=255 (pad) zero. Split into bf16 hi/lo.
// Layout: [coltile ct][kstep ks][lane][8]  (lane: col=lane&15, k=(lane>>4)*8+j)
__global__ void __launch_bounds__(256) k_wgen(
    short* __restrict__ Whi, short* __restrict__ Wlo){
  int t = blockIdx.x*256 + threadIdx.x;
  if (t >= 2*8*64) return;
  int ct = t >> 9, ks = (t >> 6) & 7, lane = t & 63;
  int col = ct*16 + (lane & 15);
  int kb = ks*32 + (lane >> 4)*8;
  for (int j=0; j<8; j++){
    int k = kb + j;
    float w = 0.f;
    if (k < 255 && col < 24){
      int m = col >> 1;
      float ang = TWOPI_N * (float)((k*m) % 255);
      w = (col & 1) ? -sinf(ang) : cosf(ang);
    }
    unsigned int hi = f2bf_u(w);
    float lo = w - bf2f_u(hi);
    Whi[t*8+j] = (short)hi;
    Wlo[t*8+j] = (short)f2bf_u(lo);
  }
}

// ---------------- forward DFT along W via split-bf16 MFMA ------------------
// GEMM: R[row, 0..23] = sum_k bnrelu(field[row][k]) * W[k][col]
// wave = 16 rows x 24 outputs; 8 K-steps of 32; 3 MFMAs/step/coltile.
__global__ void __launch_bounds__(256) k_dftw(
    const float* __restrict__ h, float* __restrict__ R,
    const short* __restrict__ Whi, const short* __restrict__ Wlo,
    const float* __restrict__ bnp, int relu){
  int t = threadIdx.x;
  int wid = t >> 6, lane = t & 63;
  int r0 = blockIdx.x*64 + wid*16;
  int rowg = r0 + (lane & 15);
  int c = (rowg / HH) & (CH-1);
  float sc = bnp[c], sh = bnp[CH+c];
  const float* rp = h + (size_t)rowg*HH;
  int koff = (lane >> 4)*8;
  f32x4 acc0 = {0.f,0.f,0.f,0.f};
  f32x4 acc1 = {0.f,0.f,0.f,0.f};
  for (int ks=0; ks<8; ks++){
    int k0 = ks*32 + koff;
    short8 ahi, alo;
    #pragma unroll
    for (int j=0; j<8; j++){
      float z = rp[k0+j];            // k=255 pad reads in-bounds junk * 0-weight
      z = z*sc + sh;
      if (relu) z = fmaxf(z, 0.f);
      unsigned int hb = f2bf_u(z);
      ahi[j] = (short)hb;
      alo[j] = (short)f2bf_u(z - bf2f_u(hb));
    }
    short8 b0h = *(const short8*)(Whi + ((size_t)(0*8+ks)*64 + lane)*8);
    short8 b0l = *(const short8*)(Wlo + ((size_t)(0*8+ks)*64 + lane)*8);
    short8 b1h = *(const short8*)(Whi + ((size_t)(1*8+ks)*64 + lane)*8);
    short8 b1l = *(const short8*)(Wlo + ((size_t)(1*8+ks)*64 + lane)*8);
    acc0 = __builtin_amdgcn_mfma_f32_16x16x32_bf16(ahi, b0h, acc0, 0,0,0);
    acc0 = __builtin_amdgcn_mfma_f32_16x16x32_bf16(ahi, b0l, acc0, 0,0,0);
    acc0 = __builtin_amdgcn_mfma_f32_16x16x32_bf16(alo, b0h, acc0, 0,0,0);
    acc1 = __builtin_amdgcn_mfma_f32_16x16x32_bf16(ahi, b1h, acc1, 0,0,0);
    acc1 = __builtin_amdgcn_mfma_f32_16x16x32_bf16(ahi, b1l, acc1, 0,0,0);
    acc1 = __builtin_amdgcn_mfma_f32_16x16x32_bf16(alo, b1h, acc1, 0,0,0);
  }
  // C/D layout (m89): col = lane&15, row = (lane>>4)*4 + q
  int colq = lane & 15;
  int rq = r0 + (lane >> 4)*4;
  #pragma unroll
  for (int q=0; q<4; q++)
    R[(size_t)(rq+q)*24 + colq] = acc0[q];
  if (colq < 8){
    #pragma unroll
    for (int q=0; q<4; q++)
      R[(size_t)(rq+q)*24 + 16 + colq] = acc1[q];
  }
}

// ---------------- forward DFT along H: R -> Xf[bc][ky24][kx12], *1/255 -----
__global__ void __launch_bounds__(320) k_dfth(
    const float* __restrict__ R, float* __restrict__ Xf){
  __shared__ float lr[HH][M2][2];
  int t = threadIdx.x, bc = blockIdx.x;
  const float4* src = (const float4*)(R + bc*(HH*M2*2));
  for (int i=t; i<(HH*M2*2)/4; i+=320) ((float4*)lr)[i] = src[i];
  __syncthreads();
  if (t < KY24*M2){
    int ky = t / M2, kx = t - (t/M2)*M2;
    int freq = (ky < M1) ? ky : (HH - KY24 + ky);  // 0..11 or 243..254
    float ang = TWOPI_N * (float)freq;
    float c1 = cosf(ang), s1 = sinf(ang);
    float cr=1.f, sr=0.f, ar=0.f, ai=0.f;
    for (int y=0; y<HH; y++){
      float rr = lr[y][kx][0], ri = lr[y][kx][1];
      ar += rr*cr + ri*sr;   // * e^{-i theta}
      ai += ri*cr - rr*sr;
      float cn = cr*c1 - sr*s1;
      sr = sr*c1 + cr*s1;
      cr = cn;
    }
    const float inv = 1.0f/255.0f;
    int o = (bc*KY24 + ky)*(M2*2) + kx*2;
    Xf[o]   = ar*inv;
    Xf[o+1] = ai*inv;
  }
}

// ---------------- per-mode 32x32 complex channel mix -----------------------
__global__ void __launch_bounds__(384) k_mix(
    const float* __restrict__ Xf, const float* __restrict__ w,
    float* __restrict__ Y){
  int m2 = blockIdx.x, blk = blockIdx.y, b = blockIdx.z;
  int t = threadIdx.x;
  __shared__ float lx[CH][M1][2];
  for (int i=t; i<CH*M1*2; i+=384){
    int ii = i/(M1*2), rem = i - ii*(M1*2);
    int m1 = rem>>1, comp = rem&1;
    lx[ii][m1][comp] = Xf[((b*CH+ii)*KY24 + blk*M1 + m1)*(M2*2) + m2*2 + comp];
  }
  __syncthreads();
  int m1 = t >> 5, o = t & 31;
  float ar=0.f, ai=0.f;
  const float* wp = w + ((blk*CH*CH + o)*M1 + m1)*(M2*2) + m2*2;
  const int istride = CH*M1*M2*2;
  for (int i=0;i<CH;i++){
    float xr = lx[i][m1][0], xi = lx[i][m1][1];
    float wr = wp[0], wi = wp[1];
    ar += xr*wr - xi*wi;
    ai += xr*wi + xi*wr;
    wp += istride;
  }
  int oidx = ((b*CH+o)*KY24 + blk*M1 + m1)*(M2*2) + m2*2;
  Y[oidx]   = ar;
  Y[oidx+1] = ai;
}

// ---------------- inverse along H: Y modes -> G[bo][y][kx] -----------------
__global__ void __launch_bounds__(256) k_idfth(
    const float* __restrict__ Y, float* __restrict__ G){
  __shared__ float ly[KY24][M2][2];
  int t = threadIdx.x, bo = blockIdx.x;
  const float4* src = (const float4*)(Y + bo*(KY24*M2*2));
  for (int i=t; i<(KY24*M2*2)/4; i+=256) ((float4*)ly)[i] = src[i];
  __syncthreads();
  const float inv = 1.0f/255.0f;
  for (int p=t; p<HH*M2; p+=256){
    int y = p/M2, kx = p - (p/M2)*M2;
    float ang = TWOPI_N * (float)y;
    float c1 = cosf(ang), s1 = sinf(ang);
    float ar = ly[0][kx][0], ai = ly[0][kx][1];
    float c = c1, s = s1;
    #pragma unroll
    for (int k=1; k<=11; k++){
      float yr = ly[k][kx][0],     yi = ly[k][kx][1];
      ar += yr*c - yi*s;                 // * T_k
      ai += yr*s + yi*c;
      float zr = ly[24-k][kx][0],  zi = ly[24-k][kx][1];
      ar += zr*c + zi*s;                 // * conj(T_k)
      ai += zi*c - zr*s;
      float cn = c*c1 - s*s1;
      s = s*c1 + c*s1;
      c = cn;
    }
    {
      float zr = ly[12][kx][0], zi = ly[12][kx][1];   // freq -12: conj(T_12)
      ar += zr*c + zi*s;
      ai += zi*c - zr*s;
    }
    float f = (kx==0) ? inv : 2.0f*inv;
    int o = (bo*HH + y)*(M2*2) + kx*2;
    G[o]   = ar*f;
    G[o+1] = ai*f;
  }
}

// ------- fused: BN-on-load + inverse along W + 1x1 conv + BN partials ------
__global__ void __launch_bounds__(256) k_fuse(
    const float* __restrict__ h, const float* __restrict__ G,
    const float* __restrict__ cw, const float* __restrict__ cb,
    float* __restrict__ tout, float* __restrict__ partials,
    const float* __restrict__ bnp, int relu){
  __shared__ float ot[CH][HH];        // output tile (for BN partial sums)
  __shared__ float red[CH][8][2];
  __shared__ float lsc[CH], lsh[CH];
  int y = blockIdx.x, b = blockIdx.y, t = threadIdx.x;
  int hbase = (b*CH*HH + y)*HH;
  if (t < CH){ lsc[t] = bnp[t]; lsh[t] = bnp[CH+t]; }
  __syncthreads();
  int xx = t;
  if (xx < HH){
    float hl[CH];
    #pragma unroll
    for (int c=0;c<CH;c++){
      float v = h[hbase + c*NPIX + xx]*lsc[c] + lsh[c];
      hl[c] = relu ? fmaxf(v, 0.f) : v;
    }
    float ck[M2], sk[M2];
    {
      float ang = TWOPI_N * (float)xx;
      ck[1] = cosf(ang); sk[1] = sinf(ang);
      #pragma unroll
      for (int k=2;k<M2;k++){
        ck[k] = ck[k-1]*ck[1] - sk[k-1]*sk[1];
        sk[k] = sk[k-1]*ck[1] + ck[k-1]*sk[1];
      }
    }
    for (int o=0;o<CH;o++){
      int gb = __builtin_amdgcn_readfirstlane(((b*CH+o)*HH + y)*(M2*2));
      const float* gp = G + gb;
      int cwb = __builtin_amdgcn_readfirstlane(o*CH);
      float acc = cb[o];
      #pragma unroll
      for (int c=0;c<CH;c++) acc += hl[c]*cw[cwb + c];
      float sp = gp[0];                  // Re(G0); imag of bin 0 ignored (C2R)
      #pragma unroll
      for (int kx=1;kx<M2;kx++)
        sp += gp[2*kx]*ck[kx] - gp[2*kx+1]*sk[kx];
      acc += sp;
      tout[hbase + o*NPIX + xx] = acc;
      ot[o][xx] = acc;
    }
  }
  __syncthreads();
  int o = t >> 3, j = t & 7;
  float s1v = 0.f, s2v = 0.f;
  for (int k=j; k<HH; k+=8){
    float v = ot[o][k];
    s1v += v; s2v += v*v;
  }
  red[o][j][0] = s1v; red[o][j][1] = s2v;
  __syncthreads();
  if (t < CH*2){
    int oo = t >> 1, st = t & 1;
    float s = 0.f;
    #pragma unroll
    for (int j2=0;j2<8;j2++) s += red[oo][j2][st];
    partials[(oo*2+st)*(BATCH*HH) + b*HH + y] = s;
  }
}

// ---------------- deterministic stats reduce -> scale/shift ----------------
__global__ void __launch_bounds__(256) k_stats(
    const float* __restrict__ partials,
    const float* __restrict__ g, const float* __restrict__ bb,
    float* __restrict__ bnp){
  __shared__ float acc[256];
  int o = blockIdx.x, t = threadIdx.x;
  int half = t >> 7, j = t & 127;
  const float* p = partials + (size_t)(o*2+half)*(BATCH*HH);
  float s = 0.f;
  for (int k=j; k<BATCH*HH; k+=128) s += p[k];
  acc[t] = s;
  __syncthreads();
  for (int w2=64; w2>0; w2>>=1){
    if (j < w2) acc[t] += acc[t+w2];
    __syncthreads();
  }
  if (t == 0){
    const float N = (float)BATCH * (float)NPIX;
    float mean = acc[0] / N;
    float var  = acc[128] / N - mean*mean;
    float iv = rsqrtf(var + 1e-5f);
    float scv = g[o]*iv;
    bnp[o]      = scv;
    bnp[CH + o] = bb[o] - mean*scv;
  }
}

// ------- final: BN(l3, no relu) + fc1 + relu + fc2, quadrant only ----------
__global__ void __launch_bounds__(128) k_final(
    const float* __restrict__ tb, const float* __restrict__ bnp,
    const float* __restrict__ w1, const float* __restrict__ b1,
    const float* __restrict__ w2, const float* __restrict__ b2,
    float* __restrict__ out){
  int yq = blockIdx.x, b = blockIdx.y, t = threadIdx.x;
  int y = (SS-1) + yq, xx = (SS-1) + t;
  float v[CH];
  int base = (b*CH*HH + y)*HH + xx;
  #pragma unroll
  for (int c=0;c<CH;c++)
    v[c] = tb[base + c*NPIX]*bnp[c] + bnp[CH+c];
  float o2 = b2[0];
  for (int d=0; d<128; d++){
    float u = b1[d];
    #pragma unroll
    for (int c=0;c<CH;c++) u += v[c]*w1[c*128 + d];
    o2 += fmaxf(u, 0.f)*w2[d];
  }
  int ob = (b*DC*SS + yq)*SS + t;
  out[ob]           = o2;
  out[ob +   SS*SS] = o2;
  out[ob + 2*SS*SS] = o2;
}

extern "C" void kernel_launch(void* const* d_in, const int* in_sizes, int n_in,
                              void* d_out, int out_size, void* d_ws, size_t ws_size,
                              hipStream_t stream) {
  (void)in_sizes; (void)n_in; (void)out_size; (void)ws_size;
  const float* x      = (const float*)d_in[0];
  const float* fc0_w  = (const float*)d_in[1];
  const float* fc0_b  = (const float*)d_in[2];
  const float* spec_w = (const float*)d_in[3];
  const float* conv_w = (const float*)d_in[4];
  const float* conv_b = (const float*)d_in[5];
  const float* bn_g   = (const float*)d_in[6];
  const float* bn_b   = (const float*)d_in[7];
  const float* fc1_w  = (const float*)d_in[8];
  const float* fc1_b  = (const float*)d_in[9];
  const float* fc2_w  = (const float*)d_in[10];
  const float* fc2_b  = (const float*)d_in[11];
  float* out = (float*)d_out;
  float* ws  = (float*)d_ws;

  const size_t NB = (size_t)BATCH*CH*NPIX;             // 33,292,800 (127 MiB)
  float* field = ws;
  float* Rbuf  = field + NB;                           // 3,133,440 (also G)
  float* Xf    = Rbuf + (size_t)NROWS*M2*2;            // 294,912
  float* Yb    = Xf   + (size_t)BATCH*CH*KY24*M2*2;    // 294,912
  float* parts = Yb   + (size_t)BATCH*CH*KY24*M2*2;    // 261,120
  float* bnp   = parts + (size_t)64*BATCH*HH;          // 5 slots x 64
  short* Whi   = (short*)(bnp + 5*64);                 // 8192 shorts
  short* Wlo   = Whi + 2*8*64*8;                       // 8192 shorts

  k_wgen<<<4, 256, 0, stream>>>(Whi, Wlo);
  k_fc0<<<dim3(HH, BATCH), 256, 0, stream>>>(x, fc0_w, fc0_b, field, bnp);

  const size_t wstride = (size_t)2*CH*CH*M1*M2*2;      // per-layer spec_w elems
  for (int l=0; l<4; l++){
    const float* bnin = bnp + (size_t)l*64;            // BN of layer l-1 (or id)
    int relu = (l >= 1);                               // ReLU after layers 0..2
    k_dftw <<<NROWS/64, 256, 0, stream>>>(field, Rbuf, Whi, Wlo, bnin, relu);
    k_dfth <<<BATCH*CH, 320, 0, stream>>>(Rbuf, Xf);
    k_mix  <<<dim3(M2, 2, BATCH), 384, 0, stream>>>(Xf, spec_w + (size_t)l*wstride, Yb);
    k_idfth<<<BATCH*CH, 256, 0, stream>>>(Yb, Rbuf);
    k_fuse <<<dim3(HH, BATCH), 256, 0, stream>>>(field, Rbuf, conv_w + l*CH*CH,
                                                 conv_b + l*CH, field, parts,
                                                 bnin, relu);
    k_stats<<<CH, 256, 0, stream>>>(parts, bn_g + l*CH, bn_b + l*CH,
                                    bnp + (size_t)(l+1)*64);
  }
  k_final<<<dim3(SS, BATCH), 128, 0, stream>>>(field, bnp + 4*64, fc1_w, fc1_b,
                                               fc2_w, fc2_b, out);
}

// Round 5
// 887.550 us; speedup vs baseline: 2.2687x; 1.0429x over previous
//
#include <hip/hip_runtime.h>

#define BATCH 16
#define CH 32
#define DC 3
#define SS 128
#define HH 255
#define M1 12
#define M2 12
#define KY24 (2*M1)
#define NPIX (HH*HH)
#define NROWS (BATCH*CH*HH)
#define TWOPI_N 0.02463994238463573f   // 2*pi/255

typedef __attribute__((ext_vector_type(8))) short short8;
typedef __attribute__((ext_vector_type(4))) float f32x4;

__device__ inline unsigned int f2bf_u(float x){
  unsigned int u = __float_as_uint(x);
  return (u + 0x7FFFu + ((u >> 16) & 1u)) >> 16;
}
__device__ inline float bf2f_u(unsigned int s){
  return __uint_as_float(s << 16);
}

// ---------------- mirror + fc0 lift (+ identity BN slot init) --------------
__global__ void __launch_bounds__(256) k_fc0(
    const float* __restrict__ x, const float* __restrict__ w,
    const float* __restrict__ bias, float* __restrict__ h,
    float* __restrict__ bnp0){
  int y = blockIdx.x, b = blockIdx.y, xx = threadIdx.x;
  if (blockIdx.x == 0 && blockIdx.y == 0 && xx < CH){
    bnp0[xx] = 1.f; bnp0[CH+xx] = 0.f;
  }
  if (xx >= HH) return;
  int iy = (y  >= SS-1) ? y  - (SS-1) : (SS-1) - y;
  int ix = (xx >= SS-1) ? xx - (SS-1) : (SS-1) - xx;
  float sgn = ((y >= SS-1) == (xx >= SS-1)) ? 1.f : -1.f;
  float v0 = sgn * x[((b*DC + 0)*SS + iy)*SS + ix];
  float v1 = sgn * x[((b*DC + 1)*SS + iy)*SS + ix];
  float v2 = sgn * x[((b*DC + 2)*SS + iy)*SS + ix];
  int base = (b*CH*HH + y)*HH + xx;
  for (int d=0; d<CH; d++){
    h[base + d*NPIX] = bias[d] + v0*w[d] + v1*w[CH+d] + v2*w[2*CH+d];
  }
}

// ------- DFT weight fragments for k_dftw (B-fragment order, bf16 hi/lo) ----
__global__ void __launch_bounds__(256) k_wgen(
    short* __restrict__ Whi, short* __restrict__ Wlo){
  int t = blockIdx.x*256 + threadIdx.x;
  if (t >= 2*8*64) return;
  int ct = t >> 9, ks = (t >> 6) & 7, lane = t & 63;
  int col = ct*16 + (lane & 15);
  int kb = ks*32 + (lane >> 4)*8;
  for (int j=0; j<8; j++){
    int k = kb + j;
    float w = 0.f;
    if (k < 255 && col < 24){
      int m = col >> 1;
      float ang = TWOPI_N * (float)((k*m) % 255);
      w = (col & 1) ? -sinf(ang) : cosf(ang);
    }
    unsigned int hi = f2bf_u(w);
    float lo = w - bf2f_u(hi);
    Whi[t*8+j] = (short)hi;
    Wlo[t*8+j] = (short)f2bf_u(lo);
  }
}

// ------- inverse-W twiddle table for k_fuse (B-fragment order) -------------
// rows j (K dim): j=0 -> 1; j=2kx-1 -> cos(2pi kx x/255); j=2kx -> -sin(...)
// rows 23..31 zero; col 255 (pad) zero. Layout [ct16][lane64][8], bf16 hi/lo.
__global__ void __launch_bounds__(256) k_tgen(
    short* __restrict__ Th, short* __restrict__ Tl){
  int t = blockIdx.x*256 + threadIdx.x;
  if (t >= 16*64) return;
  int ct = t >> 6, lane = t & 63;
  int xx = ct*16 + (lane & 15);
  int jbase = (lane >> 4)*8;
  for (int j=0; j<8; j++){
    int jg = jbase + j;
    float v = 0.f;
    if (xx < HH && jg <= 22){
      if (jg == 0) v = 1.f;
      else if (jg & 1){ int kx=(jg+1)>>1; v =  cosf(TWOPI_N*(float)((kx*xx)%255)); }
      else            { int kx= jg>>1;    v = -sinf(TWOPI_N*(float)((kx*xx)%255)); }
    }
    unsigned int hi = f2bf_u(v);
    float lo = v - bf2f_u(hi);
    Th[t*8+j] = (short)hi;
    Tl[t*8+j] = (short)f2bf_u(lo);
  }
}

// ---------------- forward DFT along W via split-bf16 MFMA ------------------
__global__ void __launch_bounds__(256) k_dftw(
    const float* __restrict__ h, float* __restrict__ R,
    const short* __restrict__ Whi, const short* __restrict__ Wlo,
    const float* __restrict__ bnp, int relu){
  int t = threadIdx.x;
  int wid = t >> 6, lane = t & 63;
  int r0 = blockIdx.x*64 + wid*16;
  int rowg = r0 + (lane & 15);
  int c = (rowg / HH) & (CH-1);
  float sc = bnp[c], sh = bnp[CH+c];
  const float* rp = h + (size_t)rowg*HH;
  int koff = (lane >> 4)*8;
  f32x4 acc0 = {0.f,0.f,0.f,0.f};
  f32x4 acc1 = {0.f,0.f,0.f,0.f};
  for (int ks=0; ks<8; ks++){
    int k0 = ks*32 + koff;
    short8 ahi, alo;
    #pragma unroll
    for (int j=0; j<8; j++){
      float z = rp[k0+j];            // k=255 pad reads in-bounds junk * 0-weight
      z = z*sc + sh;
      if (relu) z = fmaxf(z, 0.f);
      unsigned int hb = f2bf_u(z);
      ahi[j] = (short)hb;
      alo[j] = (short)f2bf_u(z - bf2f_u(hb));
    }
    short8 b0h = *(const short8*)(Whi + ((size_t)(0*8+ks)*64 + lane)*8);
    short8 b0l = *(const short8*)(Wlo + ((size_t)(0*8+ks)*64 + lane)*8);
    short8 b1h = *(const short8*)(Whi + ((size_t)(1*8+ks)*64 + lane)*8);
    short8 b1l = *(const short8*)(Wlo + ((size_t)(1*8+ks)*64 + lane)*8);
    acc0 = __builtin_amdgcn_mfma_f32_16x16x32_bf16(ahi, b0h, acc0, 0,0,0);
    acc0 = __builtin_amdgcn_mfma_f32_16x16x32_bf16(ahi, b0l, acc0, 0,0,0);
    acc0 = __builtin_amdgcn_mfma_f32_16x16x32_bf16(alo, b0h, acc0, 0,0,0);
    acc1 = __builtin_amdgcn_mfma_f32_16x16x32_bf16(ahi, b1h, acc1, 0,0,0);
    acc1 = __builtin_amdgcn_mfma_f32_16x16x32_bf16(ahi, b1l, acc1, 0,0,0);
    acc1 = __builtin_amdgcn_mfma_f32_16x16x32_bf16(alo, b1h, acc1, 0,0,0);
  }
  int colq = lane & 15;
  int rq = r0 + (lane >> 4)*4;
  #pragma unroll
  for (int q=0; q<4; q++)
    R[(size_t)(rq+q)*24 + colq] = acc0[q];
  if (colq < 8){
    #pragma unroll
    for (int q=0; q<4; q++)
      R[(size_t)(rq+q)*24 + 16 + colq] = acc1[q];
  }
}

// ---------------- forward DFT along H: R -> Xf[bc][ky24][kx12], *1/255 -----
__global__ void __launch_bounds__(320) k_dfth(
    const float* __restrict__ R, float* __restrict__ Xf){
  __shared__ float lr[HH][M2][2];
  int t = threadIdx.x, bc = blockIdx.x;
  const float4* src = (const float4*)(R + bc*(HH*M2*2));
  for (int i=t; i<(HH*M2*2)/4; i+=320) ((float4*)lr)[i] = src[i];
  __syncthreads();
  if (t < KY24*M2){
    int ky = t / M2, kx = t - (t/M2)*M2;
    int freq = (ky < M1) ? ky : (HH - KY24 + ky);  // 0..11 or 243..254
    float ang = TWOPI_N * (float)freq;
    float c1 = cosf(ang), s1 = sinf(ang);
    float cr=1.f, sr=0.f, ar=0.f, ai=0.f;
    for (int y=0; y<HH; y++){
      float rr = lr[y][kx][0], ri = lr[y][kx][1];
      ar += rr*cr + ri*sr;   // * e^{-i theta}
      ai += ri*cr - rr*sr;
      float cn = cr*c1 - sr*s1;
      sr = sr*c1 + cr*s1;
      cr = cn;
    }
    const float inv = 1.0f/255.0f;
    int o = (bc*KY24 + ky)*(M2*2) + kx*2;
    Xf[o]   = ar*inv;
    Xf[o+1] = ai*inv;
  }
}

// ---------------- per-mode 32x32 complex channel mix -----------------------
__global__ void __launch_bounds__(384) k_mix(
    const float* __restrict__ Xf, const float* __restrict__ w,
    float* __restrict__ Y){
  int m2 = blockIdx.x, blk = blockIdx.y, b = blockIdx.z;
  int t = threadIdx.x;
  __shared__ float lx[CH][M1][2];
  for (int i=t; i<CH*M1*2; i+=384){
    int ii = i/(M1*2), rem = i - ii*(M1*2);
    int m1 = rem>>1, comp = rem&1;
    lx[ii][m1][comp] = Xf[((b*CH+ii)*KY24 + blk*M1 + m1)*(M2*2) + m2*2 + comp];
  }
  __syncthreads();
  int m1 = t >> 5, o = t & 31;
  float ar=0.f, ai=0.f;
  const float* wp = w + ((blk*CH*CH + o)*M1 + m1)*(M2*2) + m2*2;
  const int istride = CH*M1*M2*2;
  for (int i=0;i<CH;i++){
    float xr = lx[i][m1][0], xi = lx[i][m1][1];
    float wr = wp[0], wi = wp[1];
    ar += xr*wr - xi*wi;
    ai += xr*wi + xi*wr;
    wp += istride;
  }
  int oidx = ((b*CH+o)*KY24 + blk*M1 + m1)*(M2*2) + m2*2;
  Y[oidx]   = ar;
  Y[oidx+1] = ai;
}

// ---------------- inverse along H: Y modes -> G[bo][y][kx] -----------------
__global__ void __launch_bounds__(256) k_idfth(
    const float* __restrict__ Y, float* __restrict__ G){
  __shared__ float ly[KY24][M2][2];
  int t = threadIdx.x, bo = blockIdx.x;
  const float4* src = (const float4*)(Y + bo*(KY24*M2*2));
  for (int i=t; i<(KY24*M2*2)/4; i+=256) ((float4*)ly)[i] = src[i];
  __syncthreads();
  const float inv = 1.0f/255.0f;
  for (int p=t; p<HH*M2; p+=256){
    int y = p/M2, kx = p - (p/M2)*M2;
    float ang = TWOPI_N * (float)y;
    float c1 = cosf(ang), s1 = sinf(ang);
    float ar = ly[0][kx][0], ai = ly[0][kx][1];
    float c = c1, s = s1;
    #pragma unroll
    for (int k=1; k<=11; k++){
      float yr = ly[k][kx][0],     yi = ly[k][kx][1];
      ar += yr*c - yi*s;                 // * T_k
      ai += yr*s + yi*c;
      float zr = ly[24-k][kx][0],  zi = ly[24-k][kx][1];
      ar += zr*c + zi*s;                 // * conj(T_k)
      ai += zi*c - zr*s;
      float cn = c*c1 - s*s1;
      s = s*c1 + c*s1;
      c = cn;
    }
    {
      float zr = ly[12][kx][0], zi = ly[12][kx][1];   // freq -12: conj(T_12)
      ar += zr*c + zi*s;
      ai += zi*c - zr*s;
    }
    float f = (kx==0) ? inv : 2.0f*inv;
    int o = (bo*HH + y)*(M2*2) + kx*2;
    G[o]   = ar*f;
    G[o+1] = ai*f;
  }
}

// ------- fused MFMA: BN+ReLU-on-load + 1x1 conv + inverse-W + BN partials --
// per (b,y): out[o][xx] = sum_c cw[o][c]*hl[c][xx] + sum_j AG[o][j]*T[j][xx]
// one M=32, N=256, K=64 GEMM; split-bf16 (3-MFMA) both K-steps.
__global__ void __launch_bounds__(256) k_fuse(
    const float* __restrict__ h, const float* __restrict__ G,
    const float* __restrict__ cw, const float* __restrict__ cb,
    float* __restrict__ tout, float* __restrict__ partials,
    const short* __restrict__ Th, const short* __restrict__ Tl,
    const float* __restrict__ bnp, int relu){
  __shared__ short Bh[16*64*8];         // conv B fragments, hi (16 KB)
  __shared__ short Bl[16*64*8];         // conv B fragments, lo (16 KB)
  __shared__ float red[CH][4][2];
  int y = blockIdx.x, b = blockIdx.y, t = threadIdx.x;
  int hbase = (b*CH*HH + y)*HH;
  // --- stage conv-B: hl[c][xx] = relu(bn(h)), fragment order, hi/lo ---
  {
    int xx = t;                          // 0..255 (255 = zero pad col)
    int ct = xx >> 4;
    #pragma unroll
    for (int ko=0; ko<4; ko++){
      short8 ph, pl;
      #pragma unroll
      for (int j=0; j<8; j++){
        int c = ko*8 + j;
        float v = 0.f;
        if (xx < HH){
          v = h[hbase + c*NPIX + xx]*bnp[c] + bnp[CH+c];
          if (relu) v = fmaxf(v, 0.f);
        }
        unsigned int hb = f2bf_u(v);
        ph[j] = (short)hb;
        pl[j] = (short)f2bf_u(v - bf2f_u(hb));
      }
      int lane = (xx & 15) | (ko << 4);
      *(short8*)(Bh + (ct*64 + lane)*8) = ph;
      *(short8*)(Bl + (ct*64 + lane)*8) = pl;
    }
  }
  // --- A fragments (registers): conv weights + spectral G row ---
  int w = t >> 6, lane = t & 63;
  int arow = lane & 15, koff = (lane >> 4)*8;
  short8 a0h[2], a0l[2], a1h[2], a1l[2];
  #pragma unroll
  for (int rt=0; rt<2; rt++){
    int o = rt*16 + arow;
    #pragma unroll
    for (int j=0; j<8; j++){
      float v = cw[o*CH + koff + j];
      unsigned int hb = f2bf_u(v);
      a0h[rt][j] = (short)hb;
      a0l[rt][j] = (short)f2bf_u(v - bf2f_u(hb));
    }
    const float* gp = G + ((size_t)(b*CH+o)*HH + y)*24;
    #pragma unroll
    for (int j=0; j<8; j++){
      int jg = koff + j;                 // jg>=23: B rows are zero -> don't care
      float v = (jg==0) ? gp[0] : gp[jg+1];
      unsigned int hb = f2bf_u(v);
      a1h[rt][j] = (short)hb;
      a1l[rt][j] = (short)f2bf_u(v - bf2f_u(hb));
    }
  }
  __syncthreads();
  // --- MFMA: each wave owns 4 col-tiles (64 xx), all 32 output rows ---
  f32x4 acc[2][4];
  #pragma unroll
  for (int rt=0; rt<2; rt++)
    #pragma unroll
    for (int cl=0; cl<4; cl++) acc[rt][cl] = (f32x4){0.f,0.f,0.f,0.f};
  #pragma unroll
  for (int cl=0; cl<4; cl++){
    int ct = w*4 + cl;
    short8 b0h = *(const short8*)(Bh + (ct*64 + lane)*8);
    short8 b0l = *(const short8*)(Bl + (ct*64 + lane)*8);
    short8 b1h = *(const short8*)(Th + ((size_t)ct*64 + lane)*8);
    short8 b1l = *(const short8*)(Tl + ((size_t)ct*64 + lane)*8);
    #pragma unroll
    for (int rt=0; rt<2; rt++){
      acc[rt][cl] = __builtin_amdgcn_mfma_f32_16x16x32_bf16(a0h[rt], b0h, acc[rt][cl], 0,0,0);
      acc[rt][cl] = __builtin_amdgcn_mfma_f32_16x16x32_bf16(a0h[rt], b0l, acc[rt][cl], 0,0,0);
      acc[rt][cl] = __builtin_amdgcn_mfma_f32_16x16x32_bf16(a0l[rt], b0h, acc[rt][cl], 0,0,0);
      acc[rt][cl] = __builtin_amdgcn_mfma_f32_16x16x32_bf16(a1h[rt], b1h, acc[rt][cl], 0,0,0);
      acc[rt][cl] = __builtin_amdgcn_mfma_f32_16x16x32_bf16(a1h[rt], b1l, acc[rt][cl], 0,0,0);
      acc[rt][cl] = __builtin_amdgcn_mfma_f32_16x16x32_bf16(a1l[rt], b1h, acc[rt][cl], 0,0,0);
    }
  }
  // --- epilogue: bias, store, BN partial sums (deterministic) ---
  float s1[2][4], s2[2][4];
  #pragma unroll
  for (int rt=0; rt<2; rt++)
    #pragma unroll
    for (int q=0; q<4; q++){ s1[rt][q]=0.f; s2[rt][q]=0.f; }
  #pragma unroll
  for (int rt=0; rt<2; rt++)
    #pragma unroll
    for (int cl=0; cl<4; cl++){
      int xxo = (w*4 + cl)*16 + (lane & 15);
      bool ok = xxo < HH;
      #pragma unroll
      for (int q=0; q<4; q++){
        int o = rt*16 + (lane >> 4)*4 + q;       // C/D layout (m89)
        float v = acc[rt][cl][q] + cb[o];
        if (ok) tout[hbase + o*NPIX + xxo] = v;
        float vv = ok ? v : 0.f;
        s1[rt][q] += vv;
        s2[rt][q] += vv*vv;
      }
    }
  #pragma unroll
  for (int rt=0; rt<2; rt++)
    #pragma unroll
    for (int q=0; q<4; q++){
      float v1 = s1[rt][q], v2 = s2[rt][q];
      #pragma unroll
      for (int off=8; off>0; off>>=1){
        v1 += __shfl_xor(v1, off, 16);
        v2 += __shfl_xor(v2, off, 16);
      }
      if ((lane & 15) == 0){
        int o = rt*16 + (lane >> 4)*4 + q;
        red[o][w][0] = v1;
        red[o][w][1] = v2;
      }
    }
  __syncthreads();
  if (t < CH*2){
    int oo = t >> 1, st = t & 1;
    float s = red[oo][0][st] + red[oo][1][st] + red[oo][2][st] + red[oo][3][st];
    partials[(oo*2+st)*(BATCH*HH) + b*HH + y] = s;
  }
}

// ---------------- deterministic stats reduce -> scale/shift ----------------
__global__ void __launch_bounds__(256) k_stats(
    const float* __restrict__ partials,
    const float* __restrict__ g, const float* __restrict__ bb,
    float* __restrict__ bnp){
  __shared__ float acc[256];
  int o = blockIdx.x, t = threadIdx.x;
  int half = t >> 7, j = t & 127;
  const float* p = partials + (size_t)(o*2+half)*(BATCH*HH);
  float s = 0.f;
  for (int k=j; k<BATCH*HH; k+=128) s += p[k];
  acc[t] = s;
  __syncthreads();
  for (int w2=64; w2>0; w2>>=1){
    if (j < w2) acc[t] += acc[t+w2];
    __syncthreads();
  }
  if (t == 0){
    const float N = (float)BATCH * (float)NPIX;
    float mean = acc[0] / N;
    float var  = acc[128] / N - mean*mean;
    float iv = rsqrtf(var + 1e-5f);
    float scv = g[o]*iv;
    bnp[o]      = scv;
    bnp[CH + o] = bb[o] - mean*scv;
  }
}

// ------- final: BN(l3, no relu) + fc1 + relu + fc2, quadrant only ----------
__global__ void __launch_bounds__(128) k_final(
    const float* __restrict__ tb, const float* __restrict__ bnp,
    const float* __restrict__ w1, const float* __restrict__ b1,
    const float* __restrict__ w2, const float* __restrict__ b2,
    float* __restrict__ out){
  int yq = blockIdx.x, b = blockIdx.y, t = threadIdx.x;
  int y = (SS-1) + yq, xx = (SS-1) + t;
  float v[CH];
  int base = (b*CH*HH + y)*HH + xx;
  #pragma unroll
  for (int c=0;c<CH;c++)
    v[c] = tb[base + c*NPIX]*bnp[c] + bnp[CH+c];
  float o2 = b2[0];
  for (int d=0; d<128; d++){
    float u = b1[d];
    #pragma unroll
    for (int c=0;c<CH;c++) u += v[c]*w1[c*128 + d];
    o2 += fmaxf(u, 0.f)*w2[d];
  }
  int ob = (b*DC*SS + yq)*SS + t;
  out[ob]           = o2;
  out[ob +   SS*SS] = o2;
  out[ob + 2*SS*SS] = o2;
}

extern "C" void kernel_launch(void* const* d_in, const int* in_sizes, int n_in,
                              void* d_out, int out_size, void* d_ws, size_t ws_size,
                              hipStream_t stream) {
  (void)in_sizes; (void)n_in; (void)out_size; (void)ws_size;
  const float* x      = (const float*)d_in[0];
  const float* fc0_w  = (const float*)d_in[1];
  const float* fc0_b  = (const float*)d_in[2];
  const float* spec_w = (const float*)d_in[3];
  const float* conv_w = (const float*)d_in[4];
  const float* conv_b = (const float*)d_in[5];
  const float* bn_g   = (const float*)d_in[6];
  const float* bn_b   = (const float*)d_in[7];
  const float* fc1_w  = (const float*)d_in[8];
  const float* fc1_b  = (const float*)d_in[9];
  const float* fc2_w  = (const float*)d_in[10];
  const float* fc2_b  = (const float*)d_in[11];
  float* out = (float*)d_out;
  float* ws  = (float*)d_ws;

  const size_t NB = (size_t)BATCH*CH*NPIX;             // 33,292,800 (127 MiB)
  float* field = ws;
  float* Rbuf  = field + NB;                           // 3,133,440 (also G)
  float* Xf    = Rbuf + (size_t)NROWS*M2*2;            // 294,912
  float* Yb    = Xf   + (size_t)BATCH*CH*KY24*M2*2;    // 294,912
  float* parts = Yb   + (size_t)BATCH*CH*KY24*M2*2;    // 261,120
  float* bnp   = parts + (size_t)64*BATCH*HH;          // 5 slots x 64
  short* Whi   = (short*)(bnp + 5*64);                 // 8192 shorts
  short* Wlo   = Whi + 2*8*64*8;                       // 8192
  short* Th    = Wlo + 2*8*64*8;                       // 8192
  short* Tl    = Th  + 16*64*8;                        // 8192

  k_wgen<<<4, 256, 0, stream>>>(Whi, Wlo);
  k_tgen<<<4, 256, 0, stream>>>(Th, Tl);
  k_fc0<<<dim3(HH, BATCH), 256, 0, stream>>>(x, fc0_w, fc0_b, field, bnp);

  const size_t wstride = (size_t)2*CH*CH*M1*M2*2;      // per-layer spec_w elems
  for (int l=0; l<4; l++){
    const float* bnin = bnp + (size_t)l*64;            // BN of layer l-1 (or id)
    int relu = (l >= 1);                               // ReLU after layers 0..2
    k_dftw <<<NROWS/64, 256, 0, stream>>>(field, Rbuf, Whi, Wlo, bnin, relu);
    k_dfth <<<BATCH*CH, 320, 0, stream>>>(Rbuf, Xf);
    k_mix  <<<dim3(M2, 2, BATCH), 384, 0, stream>>>(Xf, spec_w + (size_t)l*wstride, Yb);
    k_idfth<<<BATCH*CH, 256, 0, stream>>>(Yb, Rbuf);
    k_fuse <<<dim3(HH, BATCH), 256, 0, stream>>>(field, Rbuf, conv_w + l*CH*CH,
                                                 conv_b + l*CH, field, parts,
                                                 Th, Tl, bnin, relu);
    k_stats<<<CH, 256, 0, stream>>>(parts, bn_g + l*CH, bn_b + l*CH,
                                    bnp + (size_t)(l+1)*64);
  }
  k_final<<<dim3(SS, BATCH), 128, 0, stream>>>(field, bnp + 4*64, fc1_w, fc1_b,
                                               fc2_w, fc2_b, out);
}

// Round 6
// 721.731 us; speedup vs baseline: 2.7899x; 1.2298x over previous
//
#include <hip/hip_runtime.h>

#define BATCH 16
#define CH 32
#define DC 3
#define SS 128
#define HH 255
#define RST 256                 // padded row stride (f16, 512B-aligned rows)
#define CST (HH*RST)            // channel stride in field
#define M1 12
#define M2 12
#define KY24 (2*M1)
#define NROWS (BATCH*CH*HH)
#define TWOPI_N 0.02463994238463573f   // 2*pi/255

typedef __attribute__((ext_vector_type(8))) _Float16 f16x8;
typedef __attribute__((ext_vector_type(4))) float f32x4;

// ---------------- mirror + fc0 lift (+ identity BN slot init) --------------
__global__ void __launch_bounds__(256) k_fc0(
    const float* __restrict__ x, const float* __restrict__ w,
    const float* __restrict__ bias, _Float16* __restrict__ h,
    float* __restrict__ bnp0){
  int y = blockIdx.x, b = blockIdx.y, xx = threadIdx.x;
  if (blockIdx.x == 0 && blockIdx.y == 0 && xx < CH){
    bnp0[xx] = 1.f; bnp0[CH+xx] = 0.f;
  }
  size_t base = (size_t)(b*CH*HH + y)*RST + xx;
  if (xx >= HH){                      // pad column -> zero
    for (int d=0; d<CH; d++) h[base + (size_t)d*CST] = (_Float16)0.f;
    return;
  }
  int iy = (y  >= SS-1) ? y  - (SS-1) : (SS-1) - y;
  int ix = (xx >= SS-1) ? xx - (SS-1) : (SS-1) - xx;
  float sgn = ((y >= SS-1) == (xx >= SS-1)) ? 1.f : -1.f;
  float v0 = sgn * x[((b*DC + 0)*SS + iy)*SS + ix];
  float v1 = sgn * x[((b*DC + 1)*SS + iy)*SS + ix];
  float v2 = sgn * x[((b*DC + 2)*SS + iy)*SS + ix];
  for (int d=0; d<CH; d++){
    float v = bias[d] + v0*w[d] + v1*w[CH+d] + v2*w[2*CH+d];
    h[base + (size_t)d*CST] = (_Float16)v;
  }
}

// ------- DFT weight fragments for k_dftw (B-fragment order, f16 hi/lo) -----
// col = 2m -> cos(2*pi*k*m/255); col = 2m+1 -> -sin; cols>=24 and k=255 zero.
__global__ void __launch_bounds__(256) k_wgen(
    _Float16* __restrict__ Whi, _Float16* __restrict__ Wlo){
  int t = blockIdx.x*256 + threadIdx.x;
  if (t >= 2*8*64) return;
  int ct = t >> 9, ks = (t >> 6) & 7, lane = t & 63;
  int col = ct*16 + (lane & 15);
  int kb = ks*32 + (lane >> 4)*8;
  for (int j=0; j<8; j++){
    int k = kb + j;
    float w = 0.f;
    if (k < 255 && col < 24){
      int m = col >> 1;
      float ang = TWOPI_N * (float)((k*m) % 255);
      w = (col & 1) ? -sinf(ang) : cosf(ang);
    }
    _Float16 hi = (_Float16)w;
    Whi[t*8+j] = hi;
    Wlo[t*8+j] = (_Float16)(w - (float)hi);
  }
}

// ------- inverse-W twiddle table for k_fuse (B-fragment order, f16 hi/lo) --
// K rows j: j=0 -> 1; j=2kx-1 -> cos(2pi kx x/255); j=2kx -> -sin(...)
__global__ void __launch_bounds__(256) k_tgen(
    _Float16* __restrict__ Th, _Float16* __restrict__ Tl){
  int t = blockIdx.x*256 + threadIdx.x;
  if (t >= 16*64) return;
  int ct = t >> 6, lane = t & 63;
  int xx = ct*16 + (lane & 15);
  int jbase = (lane >> 4)*8;
  for (int j=0; j<8; j++){
    int jg = jbase + j;
    float v = 0.f;
    if (xx < HH && jg <= 22){
      if (jg == 0) v = 1.f;
      else if (jg & 1){ int kx=(jg+1)>>1; v =  cosf(TWOPI_N*(float)((kx*xx)%255)); }
      else            { int kx= jg>>1;    v = -sinf(TWOPI_N*(float)((kx*xx)%255)); }
    }
    _Float16 hi = (_Float16)v;
    Th[t*8+j] = hi;
    Tl[t*8+j] = (_Float16)(v - (float)hi);
  }
}

// ---------------- forward DFT along W via f16 MFMA (data single, W split) --
__global__ void __launch_bounds__(256) k_dftw(
    const _Float16* __restrict__ h, float* __restrict__ R,
    const _Float16* __restrict__ Whi, const _Float16* __restrict__ Wlo,
    const float* __restrict__ bnp, int relu){
  int t = threadIdx.x;
  int wid = t >> 6, lane = t & 63;
  int r0 = blockIdx.x*64 + wid*16;
  int rowg = r0 + (lane & 15);
  int c = (rowg / HH) & (CH-1);
  float sc = bnp[c], sh = bnp[CH+c];
  const _Float16* rp = h + (size_t)rowg*RST;
  int koff = (lane >> 4)*8;
  f32x4 acc0 = {0.f,0.f,0.f,0.f};
  f32x4 acc1 = {0.f,0.f,0.f,0.f};
  for (int ks=0; ks<8; ks++){
    int k0 = ks*32 + koff;
    f16x8 av = *(const f16x8*)(rp + k0);    // 16B aligned (RST=256)
    f16x8 a;
    #pragma unroll
    for (int j=0; j<8; j++){
      float z = (float)av[j]*sc + sh;
      if (relu) z = fmaxf(z, 0.f);
      a[j] = (_Float16)z;                   // k=255 pad: W row 255 is zero
    }
    f16x8 b0h = *(const f16x8*)(Whi + ((size_t)(0*8+ks)*64 + lane)*8);
    f16x8 b0l = *(const f16x8*)(Wlo + ((size_t)(0*8+ks)*64 + lane)*8);
    f16x8 b1h = *(const f16x8*)(Whi + ((size_t)(1*8+ks)*64 + lane)*8);
    f16x8 b1l = *(const f16x8*)(Wlo + ((size_t)(1*8+ks)*64 + lane)*8);
    acc0 = __builtin_amdgcn_mfma_f32_16x16x32_f16(a, b0h, acc0, 0,0,0);
    acc0 = __builtin_amdgcn_mfma_f32_16x16x32_f16(a, b0l, acc0, 0,0,0);
    acc1 = __builtin_amdgcn_mfma_f32_16x16x32_f16(a, b1h, acc1, 0,0,0);
    acc1 = __builtin_amdgcn_mfma_f32_16x16x32_f16(a, b1l, acc1, 0,0,0);
  }
  int colq = lane & 15;
  int rq = r0 + (lane >> 4)*4;
  #pragma unroll
  for (int q=0; q<4; q++)
    R[(size_t)(rq+q)*24 + colq] = acc0[q];
  if (colq < 8){
    #pragma unroll
    for (int q=0; q<4; q++)
      R[(size_t)(rq+q)*24 + 16 + colq] = acc1[q];
  }
}

// ---------------- forward DFT along H: R -> Xf[bc][ky24][kx12], *1/255 -----
__global__ void __launch_bounds__(320) k_dfth(
    const float* __restrict__ R, float* __restrict__ Xf){
  __shared__ float lr[HH][M2][2];
  int t = threadIdx.x, bc = blockIdx.x;
  const float4* src = (const float4*)(R + bc*(HH*M2*2));
  for (int i=t; i<(HH*M2*2)/4; i+=320) ((float4*)lr)[i] = src[i];
  __syncthreads();
  if (t < KY24*M2){
    int ky = t / M2, kx = t - (t/M2)*M2;
    int freq = (ky < M1) ? ky : (HH - KY24 + ky);  // 0..11 or 243..254
    float ang = TWOPI_N * (float)freq;
    float c1 = cosf(ang), s1 = sinf(ang);
    float cr=1.f, sr=0.f, ar=0.f, ai=0.f;
    for (int y=0; y<HH; y++){
      float rr = lr[y][kx][0], ri = lr[y][kx][1];
      ar += rr*cr + ri*sr;   // * e^{-i theta}
      ai += ri*cr - rr*sr;
      float cn = cr*c1 - sr*s1;
      sr = sr*c1 + cr*s1;
      cr = cn;
    }
    const float inv = 1.0f/255.0f;
    int o = (bc*KY24 + ky)*(M2*2) + kx*2;
    Xf[o]   = ar*inv;
    Xf[o+1] = ai*inv;
  }
}

// ---------------- per-mode 32x32 complex channel mix -----------------------
__global__ void __launch_bounds__(384) k_mix(
    const float* __restrict__ Xf, const float* __restrict__ w,
    float* __restrict__ Y){
  int m2 = blockIdx.x, blk = blockIdx.y, b = blockIdx.z;
  int t = threadIdx.x;
  __shared__ float lx[CH][M1][2];
  for (int i=t; i<CH*M1*2; i+=384){
    int ii = i/(M1*2), rem = i - ii*(M1*2);
    int m1 = rem>>1, comp = rem&1;
    lx[ii][m1][comp] = Xf[((b*CH+ii)*KY24 + blk*M1 + m1)*(M2*2) + m2*2 + comp];
  }
  __syncthreads();
  int m1 = t >> 5, o = t & 31;
  float ar=0.f, ai=0.f;
  const float* wp = w + ((blk*CH*CH + o)*M1 + m1)*(M2*2) + m2*2;
  const int istride = CH*M1*M2*2;
  for (int i=0;i<CH;i++){
    float xr = lx[i][m1][0], xi = lx[i][m1][1];
    float wr = wp[0], wi = wp[1];
    ar += xr*wr - xi*wi;
    ai += xr*wi + xi*wr;
    wp += istride;
  }
  int oidx = ((b*CH+o)*KY24 + blk*M1 + m1)*(M2*2) + m2*2;
  Y[oidx]   = ar;
  Y[oidx+1] = ai;
}

// ---------------- inverse along H: Y modes -> G[bo][y][kx] -----------------
__global__ void __launch_bounds__(256) k_idfth(
    const float* __restrict__ Y, float* __restrict__ G){
  __shared__ float ly[KY24][M2][2];
  int t = threadIdx.x, bo = blockIdx.x;
  const float4* src = (const float4*)(Y + bo*(KY24*M2*2));
  for (int i=t; i<(KY24*M2*2)/4; i+=256) ((float4*)ly)[i] = src[i];
  __syncthreads();
  const float inv = 1.0f/255.0f;
  for (int p=t; p<HH*M2; p+=256){
    int y = p/M2, kx = p - (p/M2)*M2;
    float ang = TWOPI_N * (float)y;
    float c1 = cosf(ang), s1 = sinf(ang);
    float ar = ly[0][kx][0], ai = ly[0][kx][1];
    float c = c1, s = s1;
    #pragma unroll
    for (int k=1; k<=11; k++){
      float yr = ly[k][kx][0],     yi = ly[k][kx][1];
      ar += yr*c - yi*s;                 // * T_k
      ai += yr*s + yi*c;
      float zr = ly[24-k][kx][0],  zi = ly[24-k][kx][1];
      ar += zr*c + zi*s;                 // * conj(T_k)
      ai += zi*c - zr*s;
      float cn = c*c1 - s*s1;
      s = s*c1 + c*s1;
      c = cn;
    }
    {
      float zr = ly[12][kx][0], zi = ly[12][kx][1];   // freq -12: conj(T_12)
      ar += zr*c + zi*s;
      ai += zi*c - zr*s;
    }
    float f = (kx==0) ? inv : 2.0f*inv;
    int o = (bo*HH + y)*(M2*2) + kx*2;
    G[o]   = ar*f;
    G[o+1] = ai*f;
  }
}

// ------- fused MFMA: BN+ReLU-on-load + 1x1 conv + inverse-W + BN partials --
// per (b,y): out[o][xx] = sum_c cw[o][c]*hl[c][xx] + sum_j AG[o][j]*T[j][xx]
// M=32, N=256, K=64; data single-f16, weight/twiddle tables split hi/lo.
__global__ void __launch_bounds__(256, 6) k_fuse(
    const _Float16* __restrict__ h, const float* __restrict__ G,
    const float* __restrict__ cw, const float* __restrict__ cb,
    _Float16* __restrict__ tout, float* __restrict__ partials,
    const _Float16* __restrict__ Th, const _Float16* __restrict__ Tl,
    const float* __restrict__ bnp, int relu){
  __shared__ _Float16 Bf[16*64*8];      // conv B fragments (16 KB)
  __shared__ float red[CH][4][2];
  int y = blockIdx.x, b = blockIdx.y, t = threadIdx.x;
  size_t hbase = (size_t)(b*CH*HH + y)*RST;
  // --- stage conv-B: hl[c][xx] = relu(bn(h)), fragment order ---
  {
    int xx = t;                          // 0..255 (255 = zero pad col)
    int ct = xx >> 4;
    #pragma unroll
    for (int ko=0; ko<4; ko++){
      f16x8 p;
      #pragma unroll
      for (int j=0; j<8; j++){
        int c = ko*8 + j;
        float v = 0.f;
        if (xx < HH){
          v = (float)h[hbase + (size_t)c*CST + xx]*bnp[c] + bnp[CH+c];
          if (relu) v = fmaxf(v, 0.f);
        }
        p[j] = (_Float16)v;
      }
      int lane = (xx & 15) | (ko << 4);
      *(f16x8*)(Bf + (ct*64 + lane)*8) = p;
    }
  }
  // --- A fragments: conv weights (split hi/lo) + spectral G row (single) ---
  int w = t >> 6, lane = t & 63;
  int arow = lane & 15, koff = (lane >> 4)*8;
  f16x8 a0h[2], a0l[2], a1[2];
  #pragma unroll
  for (int rt=0; rt<2; rt++){
    int o = rt*16 + arow;
    #pragma unroll
    for (int j=0; j<8; j++){
      float v = cw[o*CH + koff + j];
      _Float16 hi = (_Float16)v;
      a0h[rt][j] = hi;
      a0l[rt][j] = (_Float16)(v - (float)hi);
    }
    const float* gp = G + ((size_t)(b*CH+o)*HH + y)*24;
    #pragma unroll
    for (int j=0; j<8; j++){
      int jg = koff + j;                 // jg>=23: T rows are zero -> don't care
      float v = (jg==0) ? gp[0] : gp[jg+1];
      a1[rt][j] = (_Float16)v;
    }
  }
  __syncthreads();
  // --- MFMA: each wave owns 4 col-tiles (64 xx), all 32 output rows ---
  f32x4 acc[2][4];
  #pragma unroll
  for (int rt=0; rt<2; rt++)
    #pragma unroll
    for (int cl=0; cl<4; cl++) acc[rt][cl] = (f32x4){0.f,0.f,0.f,0.f};
  #pragma unroll
  for (int cl=0; cl<4; cl++){
    int ct = w*4 + cl;
    f16x8 bd = *(const f16x8*)(Bf + (ct*64 + lane)*8);
    f16x8 th = *(const f16x8*)(Th + ((size_t)ct*64 + lane)*8);
    f16x8 tl = *(const f16x8*)(Tl + ((size_t)ct*64 + lane)*8);
    #pragma unroll
    for (int rt=0; rt<2; rt++){
      acc[rt][cl] = __builtin_amdgcn_mfma_f32_16x16x32_f16(a0h[rt], bd, acc[rt][cl], 0,0,0);
      acc[rt][cl] = __builtin_amdgcn_mfma_f32_16x16x32_f16(a0l[rt], bd, acc[rt][cl], 0,0,0);
      acc[rt][cl] = __builtin_amdgcn_mfma_f32_16x16x32_f16(a1[rt], th, acc[rt][cl], 0,0,0);
      acc[rt][cl] = __builtin_amdgcn_mfma_f32_16x16x32_f16(a1[rt], tl, acc[rt][cl], 0,0,0);
    }
  }
  // --- epilogue: bias, store f16, BN partial sums (deterministic) ---
  float s1[2][4], s2[2][4];
  #pragma unroll
  for (int rt=0; rt<2; rt++)
    #pragma unroll
    for (int q=0; q<4; q++){ s1[rt][q]=0.f; s2[rt][q]=0.f; }
  #pragma unroll
  for (int rt=0; rt<2; rt++)
    #pragma unroll
    for (int cl=0; cl<4; cl++){
      int xxo = (w*4 + cl)*16 + (lane & 15);
      bool ok = xxo < HH;
      #pragma unroll
      for (int q=0; q<4; q++){
        int o = rt*16 + (lane >> 4)*4 + q;       // C/D layout (m89)
        float v = acc[rt][cl][q] + cb[o];
        if (ok) tout[hbase + (size_t)o*CST + xxo] = (_Float16)v;
        float vv = ok ? v : 0.f;
        s1[rt][q] += vv;
        s2[rt][q] += vv*vv;
      }
    }
  #pragma unroll
  for (int rt=0; rt<2; rt++)
    #pragma unroll
    for (int q=0; q<4; q++){
      float v1 = s1[rt][q], v2 = s2[rt][q];
      #pragma unroll
      for (int off=8; off>0; off>>=1){
        v1 += __shfl_xor(v1, off, 16);
        v2 += __shfl_xor(v2, off, 16);
      }
      if ((lane & 15) == 0){
        int o = rt*16 + (lane >> 4)*4 + q;
        red[o][w][0] = v1;
        red[o][w][1] = v2;
      }
    }
  __syncthreads();
  if (t < CH*2){
    int oo = t >> 1, st = t & 1;
    float s = red[oo][0][st] + red[oo][1][st] + red[oo][2][st] + red[oo][3][st];
    partials[(oo*2+st)*(BATCH*HH) + b*HH + y] = s;
  }
}

// ---------------- deterministic stats reduce -> scale/shift ----------------
__global__ void __launch_bounds__(256) k_stats(
    const float* __restrict__ partials,
    const float* __restrict__ g, const float* __restrict__ bb,
    float* __restrict__ bnp){
  __shared__ float acc[256];
  int o = blockIdx.x, t = threadIdx.x;
  int half = t >> 7, j = t & 127;
  const float* p = partials + (size_t)(o*2+half)*(BATCH*HH);
  float s = 0.f;
  for (int k=j; k<BATCH*HH; k+=128) s += p[k];
  acc[t] = s;
  __syncthreads();
  for (int w2=64; w2>0; w2>>=1){
    if (j < w2) acc[t] += acc[t+w2];
    __syncthreads();
  }
  if (t == 0){
    const float N = (float)BATCH * (float)(HH*HH);
    float mean = acc[0] / N;
    float var  = acc[128] / N - mean*mean;
    float iv = rsqrtf(var + 1e-5f);
    float scv = g[o]*iv;
    bnp[o]      = scv;
    bnp[CH + o] = bb[o] - mean*scv;
  }
}

// ------- final: BN(l3, no relu) + fc1 + relu + fc2, quadrant only ----------
__global__ void __launch_bounds__(128) k_final(
    const _Float16* __restrict__ tb, const float* __restrict__ bnp,
    const float* __restrict__ w1, const float* __restrict__ b1,
    const float* __restrict__ w2, const float* __restrict__ b2,
    float* __restrict__ out){
  int yq = blockIdx.x, b = blockIdx.y, t = threadIdx.x;
  int y = (SS-1) + yq, xx = (SS-1) + t;
  float v[CH];
  size_t base = (size_t)(b*CH*HH + y)*RST + xx;
  #pragma unroll
  for (int c=0;c<CH;c++)
    v[c] = (float)tb[base + (size_t)c*CST]*bnp[c] + bnp[CH+c];
  float o2 = b2[0];
  for (int d=0; d<128; d++){
    float u = b1[d];
    #pragma unroll
    for (int c=0;c<CH;c++) u += v[c]*w1[c*128 + d];
    o2 += fmaxf(u, 0.f)*w2[d];
  }
  int ob = (b*DC*SS + yq)*SS + t;
  out[ob]           = o2;
  out[ob +   SS*SS] = o2;
  out[ob + 2*SS*SS] = o2;
}

extern "C" void kernel_launch(void* const* d_in, const int* in_sizes, int n_in,
                              void* d_out, int out_size, void* d_ws, size_t ws_size,
                              hipStream_t stream) {
  (void)in_sizes; (void)n_in; (void)out_size; (void)ws_size;
  const float* x      = (const float*)d_in[0];
  const float* fc0_w  = (const float*)d_in[1];
  const float* fc0_b  = (const float*)d_in[2];
  const float* spec_w = (const float*)d_in[3];
  const float* conv_w = (const float*)d_in[4];
  const float* conv_b = (const float*)d_in[5];
  const float* bn_g   = (const float*)d_in[6];
  const float* bn_b   = (const float*)d_in[7];
  const float* fc1_w  = (const float*)d_in[8];
  const float* fc1_b  = (const float*)d_in[9];
  const float* fc2_w  = (const float*)d_in[10];
  const float* fc2_b  = (const float*)d_in[11];
  float* out = (float*)d_out;
  float* ws  = (float*)d_ws;

  // field: 16*32*255*256 f16 = 33,423,360 halves = 16,711,680 floats (~64 MiB)
  _Float16* field = (_Float16*)ws;
  float* Rbuf  = ws + 16711680;                        // NROWS*24 = 3,133,440
  float* Xf    = Rbuf + (size_t)NROWS*24;              // 294,912
  float* Yb    = Xf   + (size_t)BATCH*CH*KY24*M2*2;    // 294,912
  float* parts = Yb   + (size_t)BATCH*CH*KY24*M2*2;    // 261,120
  float* bnp   = parts + (size_t)64*BATCH*HH;          // 5 slots x 64
  _Float16* Whi = (_Float16*)(bnp + 5*64);             // 8192 halves each
  _Float16* Wlo = Whi + 2*8*64*8;
  _Float16* Th  = Wlo + 2*8*64*8;
  _Float16* Tl  = Th  + 16*64*8;

  k_wgen<<<4, 256, 0, stream>>>(Whi, Wlo);
  k_tgen<<<4, 256, 0, stream>>>(Th, Tl);
  k_fc0<<<dim3(HH, BATCH), 256, 0, stream>>>(x, fc0_w, fc0_b, field, bnp);

  const size_t wstride = (size_t)2*CH*CH*M1*M2*2;      // per-layer spec_w elems
  for (int l=0; l<4; l++){
    const float* bnin = bnp + (size_t)l*64;            // BN of layer l-1 (or id)
    int relu = (l >= 1);                               // ReLU after layers 0..2
    k_dftw <<<NROWS/64, 256, 0, stream>>>(field, Rbuf, Whi, Wlo, bnin, relu);
    k_dfth <<<BATCH*CH, 320, 0, stream>>>(Rbuf, Xf);
    k_mix  <<<dim3(M2, 2, BATCH), 384, 0, stream>>>(Xf, spec_w + (size_t)l*wstride, Yb);
    k_idfth<<<BATCH*CH, 256, 0, stream>>>(Yb, Rbuf);
    k_fuse <<<dim3(HH, BATCH), 256, 0, stream>>>(field, Rbuf, conv_w + l*CH*CH,
                                                 conv_b + l*CH, field, parts,
                                                 Th, Tl, bnin, relu);
    k_stats<<<CH, 256, 0, stream>>>(parts, bn_g + l*CH, bn_b + l*CH,
                                    bnp + (size_t)(l+1)*64);
  }
  k_final<<<dim3(SS, BATCH), 128, 0, stream>>>(field, bnp + 4*64, fc1_w, fc1_b,
                                               fc2_w, fc2_b, out);
}

// Round 7
// 657.802 us; speedup vs baseline: 3.0611x; 1.0972x over previous
//
#include <hip/hip_runtime.h>

#define BATCH 16
#define CH 32
#define DC 3
#define SS 128
#define HH 255
#define RST 256                 // padded row stride (f16, 512B-aligned rows)
#define CST (HH*RST)            // channel stride in field
#define M1 12
#define M2 12
#define KY24 (2*M1)
#define NROWS (BATCH*CH*HH)
#define TWOPI_N 0.02463994238463573f   // 2*pi/255

typedef __attribute__((ext_vector_type(8))) _Float16 f16x8;
typedef __attribute__((ext_vector_type(4))) float f32x4;

// ---------------- mirror + fc0 lift (+ identity BN slot init) --------------
__global__ void __launch_bounds__(256) k_fc0(
    const float* __restrict__ x, const float* __restrict__ w,
    const float* __restrict__ bias, _Float16* __restrict__ h,
    float* __restrict__ bnp0){
  int y = blockIdx.x, b = blockIdx.y, xx = threadIdx.x;
  if (blockIdx.x == 0 && blockIdx.y == 0 && xx < CH){
    bnp0[xx] = 1.f; bnp0[CH+xx] = 0.f;
  }
  size_t base = (size_t)(b*CH*HH + y)*RST + xx;
  if (xx >= HH){                      // pad column -> zero
    for (int d=0; d<CH; d++) h[base + (size_t)d*CST] = (_Float16)0.f;
    return;
  }
  int iy = (y  >= SS-1) ? y  - (SS-1) : (SS-1) - y;
  int ix = (xx >= SS-1) ? xx - (SS-1) : (SS-1) - xx;
  float sgn = ((y >= SS-1) == (xx >= SS-1)) ? 1.f : -1.f;
  float v0 = sgn * x[((b*DC + 0)*SS + iy)*SS + ix];
  float v1 = sgn * x[((b*DC + 1)*SS + iy)*SS + ix];
  float v2 = sgn * x[((b*DC + 2)*SS + iy)*SS + ix];
  for (int d=0; d<CH; d++){
    float v = bias[d] + v0*w[d] + v1*w[CH+d] + v2*w[2*CH+d];
    h[base + (size_t)d*CST] = (_Float16)v;
  }
}

// ------- DFT weight fragments for k_dftw (B-fragment order, f16 hi/lo) -----
__global__ void __launch_bounds__(256) k_wgen(
    _Float16* __restrict__ Whi, _Float16* __restrict__ Wlo){
  int t = blockIdx.x*256 + threadIdx.x;
  if (t >= 2*8*64) return;
  int ct = t >> 9, ks = (t >> 6) & 7, lane = t & 63;
  int col = ct*16 + (lane & 15);
  int kb = ks*32 + (lane >> 4)*8;
  for (int j=0; j<8; j++){
    int k = kb + j;
    float w = 0.f;
    if (k < 255 && col < 24){
      int m = col >> 1;
      float ang = TWOPI_N * (float)((k*m) % 255);
      w = (col & 1) ? -sinf(ang) : cosf(ang);
    }
    _Float16 hi = (_Float16)w;
    Whi[t*8+j] = hi;
    Wlo[t*8+j] = (_Float16)(w - (float)hi);
  }
}

// ------- inverse-W twiddle table for k_fuse (B-fragment order, f16 hi/lo) --
__global__ void __launch_bounds__(256) k_tgen(
    _Float16* __restrict__ Th, _Float16* __restrict__ Tl){
  int t = blockIdx.x*256 + threadIdx.x;
  if (t >= 16*64) return;
  int ct = t >> 6, lane = t & 63;
  int xx = ct*16 + (lane & 15);
  int jbase = (lane >> 4)*8;
  for (int j=0; j<8; j++){
    int jg = jbase + j;
    float v = 0.f;
    if (xx < HH && jg <= 22){
      if (jg == 0) v = 1.f;
      else if (jg & 1){ int kx=(jg+1)>>1; v =  cosf(TWOPI_N*(float)((kx*xx)%255)); }
      else            { int kx= jg>>1;    v = -sinf(TWOPI_N*(float)((kx*xx)%255)); }
    }
    _Float16 hi = (_Float16)v;
    Th[t*8+j] = hi;
    Tl[t*8+j] = (_Float16)(v - (float)hi);
  }
}

// ------- fc1 weight fragments (B-fragment order, f16 hi/lo) ----------------
// nt in 0..7 (fc1 dim tiles), k = channel; value = fc1_w[k*128 + nt*16+col]
__global__ void __launch_bounds__(256) k_w1gen(
    const float* __restrict__ w1, _Float16* __restrict__ W1h,
    _Float16* __restrict__ W1l){
  int t = blockIdx.x*256 + threadIdx.x;
  if (t >= 8*64) return;
  int nt = t >> 6, lane = t & 63;
  int col = nt*16 + (lane & 15);
  int kb = (lane >> 4)*8;
  for (int j=0; j<8; j++){
    float v = w1[(kb+j)*128 + col];
    _Float16 hi = (_Float16)v;
    W1h[t*8+j] = hi;
    W1l[t*8+j] = (_Float16)(v - (float)hi);
  }
}

// ---------------- forward DFT along W via f16 MFMA (data single, W split) --
__global__ void __launch_bounds__(256) k_dftw(
    const _Float16* __restrict__ h, float* __restrict__ R,
    const _Float16* __restrict__ Whi, const _Float16* __restrict__ Wlo,
    const float* __restrict__ bnp, int relu){
  int t = threadIdx.x;
  int wid = t >> 6, lane = t & 63;
  int r0 = blockIdx.x*64 + wid*16;
  int rowg = r0 + (lane & 15);
  int c = (rowg / HH) & (CH-1);
  float sc = bnp[c], sh = bnp[CH+c];
  const _Float16* rp = h + (size_t)rowg*RST;
  int koff = (lane >> 4)*8;
  f32x4 acc0 = {0.f,0.f,0.f,0.f};
  f32x4 acc1 = {0.f,0.f,0.f,0.f};
  for (int ks=0; ks<8; ks++){
    int k0 = ks*32 + koff;
    f16x8 av = *(const f16x8*)(rp + k0);    // 16B aligned (RST=256)
    f16x8 a;
    #pragma unroll
    for (int j=0; j<8; j++){
      float z = (float)av[j]*sc + sh;
      if (relu) z = fmaxf(z, 0.f);
      a[j] = (_Float16)z;                   // k=255 pad: W row 255 is zero
    }
    f16x8 b0h = *(const f16x8*)(Whi + ((size_t)(0*8+ks)*64 + lane)*8);
    f16x8 b0l = *(const f16x8*)(Wlo + ((size_t)(0*8+ks)*64 + lane)*8);
    f16x8 b1h = *(const f16x8*)(Whi + ((size_t)(1*8+ks)*64 + lane)*8);
    f16x8 b1l = *(const f16x8*)(Wlo + ((size_t)(1*8+ks)*64 + lane)*8);
    acc0 = __builtin_amdgcn_mfma_f32_16x16x32_f16(a, b0h, acc0, 0,0,0);
    acc0 = __builtin_amdgcn_mfma_f32_16x16x32_f16(a, b0l, acc0, 0,0,0);
    acc1 = __builtin_amdgcn_mfma_f32_16x16x32_f16(a, b1h, acc1, 0,0,0);
    acc1 = __builtin_amdgcn_mfma_f32_16x16x32_f16(a, b1l, acc1, 0,0,0);
  }
  int colq = lane & 15;
  int rq = r0 + (lane >> 4)*4;
  #pragma unroll
  for (int q=0; q<4; q++)
    R[(size_t)(rq+q)*24 + colq] = acc0[q];
  if (colq < 8){
    #pragma unroll
    for (int q=0; q<4; q++)
      R[(size_t)(rq+q)*24 + 16 + colq] = acc1[q];
  }
}

// ---------------- forward DFT along H: R -> Xf[bc][ky24][kx12], *1/255 -----
__global__ void __launch_bounds__(320) k_dfth(
    const float* __restrict__ R, float* __restrict__ Xf){
  __shared__ float lr[HH][M2][2];
  int t = threadIdx.x, bc = blockIdx.x;
  const float4* src = (const float4*)(R + bc*(HH*M2*2));
  for (int i=t; i<(HH*M2*2)/4; i+=320) ((float4*)lr)[i] = src[i];
  __syncthreads();
  if (t < KY24*M2){
    int ky = t / M2, kx = t - (t/M2)*M2;
    int freq = (ky < M1) ? ky : (HH - KY24 + ky);  // 0..11 or 243..254
    float ang = TWOPI_N * (float)freq;
    float c1 = cosf(ang), s1 = sinf(ang);
    float cr=1.f, sr=0.f, ar=0.f, ai=0.f;
    for (int y=0; y<HH; y++){
      float rr = lr[y][kx][0], ri = lr[y][kx][1];
      ar += rr*cr + ri*sr;   // * e^{-i theta}
      ai += ri*cr - rr*sr;
      float cn = cr*c1 - sr*s1;
      sr = sr*c1 + cr*s1;
      cr = cn;
    }
    const float inv = 1.0f/255.0f;
    int o = (bc*KY24 + ky)*(M2*2) + kx*2;
    Xf[o]   = ar*inv;
    Xf[o+1] = ai*inv;
  }
}

// ---------------- per-mode 32x32 complex channel mix -----------------------
__global__ void __launch_bounds__(384) k_mix(
    const float* __restrict__ Xf, const float* __restrict__ w,
    float* __restrict__ Y){
  int m2 = blockIdx.x, blk = blockIdx.y, b = blockIdx.z;
  int t = threadIdx.x;
  __shared__ float lx[CH][M1][2];
  for (int i=t; i<CH*M1*2; i+=384){
    int ii = i/(M1*2), rem = i - ii*(M1*2);
    int m1 = rem>>1, comp = rem&1;
    lx[ii][m1][comp] = Xf[((b*CH+ii)*KY24 + blk*M1 + m1)*(M2*2) + m2*2 + comp];
  }
  __syncthreads();
  int m1 = t >> 5, o = t & 31;
  float ar=0.f, ai=0.f;
  const float* wp = w + ((blk*CH*CH + o)*M1 + m1)*(M2*2) + m2*2;
  const int istride = CH*M1*M2*2;
  for (int i=0;i<CH;i++){
    float xr = lx[i][m1][0], xi = lx[i][m1][1];
    float wr = wp[0], wi = wp[1];
    ar += xr*wr - xi*wi;
    ai += xr*wi + xi*wr;
    wp += istride;
  }
  int oidx = ((b*CH+o)*KY24 + blk*M1 + m1)*(M2*2) + m2*2;
  Y[oidx]   = ar;
  Y[oidx+1] = ai;
}

// ---------------- inverse along H: Y modes -> G[bo][y][kx] -----------------
__global__ void __launch_bounds__(256) k_idfth(
    const float* __restrict__ Y, float* __restrict__ G){
  __shared__ float ly[KY24][M2][2];
  int t = threadIdx.x, bo = blockIdx.x;
  const float4* src = (const float4*)(Y + bo*(KY24*M2*2));
  for (int i=t; i<(KY24*M2*2)/4; i+=256) ((float4*)ly)[i] = src[i];
  __syncthreads();
  const float inv = 1.0f/255.0f;
  for (int p=t; p<HH*M2; p+=256){
    int y = p/M2, kx = p - (p/M2)*M2;
    float ang = TWOPI_N * (float)y;
    float c1 = cosf(ang), s1 = sinf(ang);
    float ar = ly[0][kx][0], ai = ly[0][kx][1];
    float c = c1, s = s1;
    #pragma unroll
    for (int k=1; k<=11; k++){
      float yr = ly[k][kx][0],     yi = ly[k][kx][1];
      ar += yr*c - yi*s;                 // * T_k
      ai += yr*s + yi*c;
      float zr = ly[24-k][kx][0],  zi = ly[24-k][kx][1];
      ar += zr*c + zi*s;                 // * conj(T_k)
      ai += zi*c - zr*s;
      float cn = c*c1 - s*s1;
      s = s*c1 + c*s1;
      c = cn;
    }
    {
      float zr = ly[12][kx][0], zi = ly[12][kx][1];   // freq -12: conj(T_12)
      ar += zr*c + zi*s;
      ai += zi*c - zr*s;
    }
    float f = (kx==0) ? inv : 2.0f*inv;
    int o = (bo*HH + y)*(M2*2) + kx*2;
    G[o]   = ar*f;
    G[o+1] = ai*f;
  }
}

// ------- fused MFMA: BN+ReLU-on-load + 1x1 conv + inverse-W + BN partials --
__global__ void __launch_bounds__(256, 6) k_fuse(
    const _Float16* __restrict__ h, const float* __restrict__ G,
    const float* __restrict__ cw, const float* __restrict__ cb,
    _Float16* __restrict__ tout, float* __restrict__ partials,
    const _Float16* __restrict__ Th, const _Float16* __restrict__ Tl,
    const float* __restrict__ bnp, int relu){
  __shared__ _Float16 Bf[16*64*8];      // conv B fragments (16 KB)
  __shared__ float red[CH][4][2];
  int y = blockIdx.x, b = blockIdx.y, t = threadIdx.x;
  size_t hbase = (size_t)(b*CH*HH + y)*RST;
  // --- stage conv-B: hl[c][xx] = relu(bn(h)), fragment order ---
  {
    int xx = t;                          // 0..255 (255 = zero pad col)
    int ct = xx >> 4;
    #pragma unroll
    for (int ko=0; ko<4; ko++){
      f16x8 p;
      #pragma unroll
      for (int j=0; j<8; j++){
        int c = ko*8 + j;
        float v = 0.f;
        if (xx < HH){
          v = (float)h[hbase + (size_t)c*CST + xx]*bnp[c] + bnp[CH+c];
          if (relu) v = fmaxf(v, 0.f);
        }
        p[j] = (_Float16)v;
      }
      int lane = (xx & 15) | (ko << 4);
      *(f16x8*)(Bf + (ct*64 + lane)*8) = p;
    }
  }
  // --- A fragments: conv weights (split hi/lo) + spectral G row (single) ---
  int w = t >> 6, lane = t & 63;
  int arow = lane & 15, koff = (lane >> 4)*8;
  f16x8 a0h[2], a0l[2], a1[2];
  #pragma unroll
  for (int rt=0; rt<2; rt++){
    int o = rt*16 + arow;
    #pragma unroll
    for (int j=0; j<8; j++){
      float v = cw[o*CH + koff + j];
      _Float16 hi = (_Float16)v;
      a0h[rt][j] = hi;
      a0l[rt][j] = (_Float16)(v - (float)hi);
    }
    const float* gp = G + ((size_t)(b*CH+o)*HH + y)*24;
    #pragma unroll
    for (int j=0; j<8; j++){
      int jg = koff + j;                 // jg>=23: T rows are zero -> don't care
      float v = (jg==0) ? gp[0] : gp[jg+1];
      a1[rt][j] = (_Float16)v;
    }
  }
  __syncthreads();
  // --- MFMA: each wave owns 4 col-tiles (64 xx), all 32 output rows ---
  f32x4 acc[2][4];
  #pragma unroll
  for (int rt=0; rt<2; rt++)
    #pragma unroll
    for (int cl=0; cl<4; cl++) acc[rt][cl] = (f32x4){0.f,0.f,0.f,0.f};
  #pragma unroll
  for (int cl=0; cl<4; cl++){
    int ct = w*4 + cl;
    f16x8 bd = *(const f16x8*)(Bf + (ct*64 + lane)*8);
    f16x8 th = *(const f16x8*)(Th + ((size_t)ct*64 + lane)*8);
    f16x8 tl = *(const f16x8*)(Tl + ((size_t)ct*64 + lane)*8);
    #pragma unroll
    for (int rt=0; rt<2; rt++){
      acc[rt][cl] = __builtin_amdgcn_mfma_f32_16x16x32_f16(a0h[rt], bd, acc[rt][cl], 0,0,0);
      acc[rt][cl] = __builtin_amdgcn_mfma_f32_16x16x32_f16(a0l[rt], bd, acc[rt][cl], 0,0,0);
      acc[rt][cl] = __builtin_amdgcn_mfma_f32_16x16x32_f16(a1[rt], th, acc[rt][cl], 0,0,0);
      acc[rt][cl] = __builtin_amdgcn_mfma_f32_16x16x32_f16(a1[rt], tl, acc[rt][cl], 0,0,0);
    }
  }
  // --- epilogue: bias, store f16, BN partial sums (deterministic) ---
  float s1[2][4], s2[2][4];
  #pragma unroll
  for (int rt=0; rt<2; rt++)
    #pragma unroll
    for (int q=0; q<4; q++){ s1[rt][q]=0.f; s2[rt][q]=0.f; }
  #pragma unroll
  for (int rt=0; rt<2; rt++)
    #pragma unroll
    for (int cl=0; cl<4; cl++){
      int xxo = (w*4 + cl)*16 + (lane & 15);
      bool ok = xxo < HH;
      #pragma unroll
      for (int q=0; q<4; q++){
        int o = rt*16 + (lane >> 4)*4 + q;       // C/D layout (m89)
        float v = acc[rt][cl][q] + cb[o];
        if (ok) tout[hbase + (size_t)o*CST + xxo] = (_Float16)v;
        float vv = ok ? v : 0.f;
        s1[rt][q] += vv;
        s2[rt][q] += vv*vv;
      }
    }
  #pragma unroll
  for (int rt=0; rt<2; rt++)
    #pragma unroll
    for (int q=0; q<4; q++){
      float v1 = s1[rt][q], v2 = s2[rt][q];
      #pragma unroll
      for (int off=8; off>0; off>>=1){
        v1 += __shfl_xor(v1, off, 16);
        v2 += __shfl_xor(v2, off, 16);
      }
      if ((lane & 15) == 0){
        int o = rt*16 + (lane >> 4)*4 + q;
        red[o][w][0] = v1;
        red[o][w][1] = v2;
      }
    }
  __syncthreads();
  if (t < CH*2){
    int oo = t >> 1, st = t & 1;
    float s = red[oo][0][st] + red[oo][1][st] + red[oo][2][st] + red[oo][3][st];
    partials[(oo*2+st)*(BATCH*HH) + b*HH + y] = s;
  }
}

// ---------------- deterministic stats reduce -> scale/shift ----------------
__global__ void __launch_bounds__(256) k_stats(
    const float* __restrict__ partials,
    const float* __restrict__ g, const float* __restrict__ bb,
    float* __restrict__ bnp){
  __shared__ float acc[256];
  int o = blockIdx.x, t = threadIdx.x;
  int half = t >> 7, j = t & 127;
  const float* p = partials + (size_t)(o*2+half)*(BATCH*HH);
  float s = 0.f;
  for (int k=j; k<BATCH*HH; k+=128) s += p[k];
  acc[t] = s;
  __syncthreads();
  for (int w2=64; w2>0; w2>>=1){
    if (j < w2) acc[t] += acc[t+w2];
    __syncthreads();
  }
  if (t == 0){
    const float N = (float)BATCH * (float)(HH*HH);
    float mean = acc[0] / N;
    float var  = acc[128] / N - mean*mean;
    float iv = rsqrtf(var + 1e-5f);
    float scv = g[o]*iv;
    bnp[o]      = scv;
    bnp[CH + o] = bb[o] - mean*scv;
  }
}

// ------- final MFMA: BN(l3) + fc1 + relu + fc2, quadrant only --------------
// per (b, yq): V (128 px x 32 ch) @ W1 (32 x 128) -> relu -> dot w2 -> out
__global__ void __launch_bounds__(256) k_final(
    const _Float16* __restrict__ tb, const float* __restrict__ bnp,
    const _Float16* __restrict__ W1h, const _Float16* __restrict__ W1l,
    const float* __restrict__ b1, const float* __restrict__ w2,
    const float* __restrict__ b2, float* __restrict__ out){
  __shared__ _Float16 Vf[128][40];      // pixel-major, 80B row stride
  int yq = blockIdx.x, b = blockIdx.y, t = threadIdx.x;
  int y = (SS-1) + yq;
  for (int i=t; i<CH*SS; i+=256){
    int c = i >> 7, xx = i & 127;
    float v = (float)tb[((size_t)(b*CH + c)*HH + y)*RST + (SS-1) + xx]
              * bnp[c] + bnp[CH+c];
    Vf[xx][c] = (_Float16)v;
  }
  __syncthreads();
  int w = t >> 6, lane = t & 63;
  int prow = lane & 15, koff = (lane >> 4)*8, col = lane & 15;
  f16x8 a0 = *(const f16x8*)&Vf[w*32 + prow][koff];
  f16x8 a1 = *(const f16x8*)&Vf[w*32 + 16 + prow][koff];
  float s0[4] = {0.f,0.f,0.f,0.f}, s1[4] = {0.f,0.f,0.f,0.f};
  #pragma unroll
  for (int nt=0; nt<8; nt++){
    f16x8 bh = *(const f16x8*)(W1h + ((size_t)nt*64 + lane)*8);
    f16x8 bl = *(const f16x8*)(W1l + ((size_t)nt*64 + lane)*8);
    f32x4 acc0 = {0.f,0.f,0.f,0.f}, acc1 = {0.f,0.f,0.f,0.f};
    acc0 = __builtin_amdgcn_mfma_f32_16x16x32_f16(a0, bh, acc0, 0,0,0);
    acc0 = __builtin_amdgcn_mfma_f32_16x16x32_f16(a0, bl, acc0, 0,0,0);
    acc1 = __builtin_amdgcn_mfma_f32_16x16x32_f16(a1, bh, acc1, 0,0,0);
    acc1 = __builtin_amdgcn_mfma_f32_16x16x32_f16(a1, bl, acc1, 0,0,0);
    float b1v = b1[nt*16 + col];
    float w2v = w2[nt*16 + col];
    #pragma unroll
    for (int q=0; q<4; q++){
      s0[q] += fmaxf(acc0[q] + b1v, 0.f)*w2v;
      s1[q] += fmaxf(acc1[q] + b1v, 0.f)*w2v;
    }
  }
  float o2b = b2[0];
  #pragma unroll
  for (int q=0; q<4; q++){
    float v0 = s0[q], v1 = s1[q];
    #pragma unroll
    for (int off=8; off>0; off>>=1){
      v0 += __shfl_xor(v0, off, 16);
      v1 += __shfl_xor(v1, off, 16);
    }
    if (col == (unsigned)q){           // one writer per pixel, deterministic
      int p0 = w*32 + (lane >> 4)*4 + q;
      int p1 = p0 + 16;
      float r0 = v0 + o2b, r1 = v1 + o2b;
      int ob = (b*DC)*SS*SS + yq*SS;
      #pragma unroll
      for (int cc=0; cc<DC; cc++){
        out[ob + cc*SS*SS + p0] = r0;
        out[ob + cc*SS*SS + p1] = r1;
      }
    }
  }
}

extern "C" void kernel_launch(void* const* d_in, const int* in_sizes, int n_in,
                              void* d_out, int out_size, void* d_ws, size_t ws_size,
                              hipStream_t stream) {
  (void)in_sizes; (void)n_in; (void)out_size; (void)ws_size;
  const float* x      = (const float*)d_in[0];
  const float* fc0_w  = (const float*)d_in[1];
  const float* fc0_b  = (const float*)d_in[2];
  const float* spec_w = (const float*)d_in[3];
  const float* conv_w = (const float*)d_in[4];
  const float* conv_b = (const float*)d_in[5];
  const float* bn_g   = (const float*)d_in[6];
  const float* bn_b   = (const float*)d_in[7];
  const float* fc1_w  = (const float*)d_in[8];
  const float* fc1_b  = (const float*)d_in[9];
  const float* fc2_w  = (const float*)d_in[10];
  const float* fc2_b  = (const float*)d_in[11];
  float* out = (float*)d_out;
  float* ws  = (float*)d_ws;

  // field: 16*32*255*256 f16 = 33,423,360 halves = 16,711,680 floats (~64 MiB)
  _Float16* field = (_Float16*)ws;
  float* Rbuf  = ws + 16711680;                        // NROWS*24 = 3,133,440
  float* Xf    = Rbuf + (size_t)NROWS*24;              // 294,912
  float* Yb    = Xf   + (size_t)BATCH*CH*KY24*M2*2;    // 294,912
  float* parts = Yb   + (size_t)BATCH*CH*KY24*M2*2;    // 261,120
  float* bnp   = parts + (size_t)64*BATCH*HH;          // 5 slots x 64
  _Float16* Whi = (_Float16*)(bnp + 5*64);             // 8192 halves each
  _Float16* Wlo = Whi + 2*8*64*8;
  _Float16* Th  = Wlo + 2*8*64*8;
  _Float16* Tl  = Th  + 16*64*8;
  _Float16* W1h = Tl  + 16*64*8;                       // 4096 halves each
  _Float16* W1l = W1h + 8*64*8;

  k_wgen<<<4, 256, 0, stream>>>(Whi, Wlo);
  k_tgen<<<4, 256, 0, stream>>>(Th, Tl);
  k_w1gen<<<2, 256, 0, stream>>>(fc1_w, W1h, W1l);
  k_fc0<<<dim3(HH, BATCH), 256, 0, stream>>>(x, fc0_w, fc0_b, field, bnp);

  const size_t wstride = (size_t)2*CH*CH*M1*M2*2;      // per-layer spec_w elems
  for (int l=0; l<4; l++){
    const float* bnin = bnp + (size_t)l*64;            // BN of layer l-1 (or id)
    int relu = (l >= 1);                               // ReLU after layers 0..2
    k_dftw <<<NROWS/64, 256, 0, stream>>>(field, Rbuf, Whi, Wlo, bnin, relu);
    k_dfth <<<BATCH*CH, 320, 0, stream>>>(Rbuf, Xf);
    k_mix  <<<dim3(M2, 2, BATCH), 384, 0, stream>>>(Xf, spec_w + (size_t)l*wstride, Yb);
    k_idfth<<<BATCH*CH, 256, 0, stream>>>(Yb, Rbuf);
    k_fuse <<<dim3(HH, BATCH), 256, 0, stream>>>(field, Rbuf, conv_w + l*CH*CH,
                                                 conv_b + l*CH, field, parts,
                                                 Th, Tl, bnin, relu);
    k_stats<<<CH, 256, 0, stream>>>(parts, bn_g + l*CH, bn_b + l*CH,
                                    bnp + (size_t)(l+1)*64);
  }
  k_final<<<dim3(SS, BATCH), 256, 0, stream>>>(field, bnp + 4*64, W1h, W1l,
                                               fc1_b, fc2_w, fc2_b, out);
}

// Round 8
// 591.536 us; speedup vs baseline: 3.4040x; 1.1120x over previous
//
#include <hip/hip_runtime.h>

#define BATCH 16
#define CH 32
#define DC 3
#define SS 128
#define HH 255
#define RST 256                 // padded row stride (f16, 512B-aligned rows)
#define CST (HH*RST)            // channel stride in field
#define M1 12
#define M2 12
#define KY24 (2*M1)
#define NROWS (BATCH*CH*HH)
#define TWOPI_N 0.02463994238463573f   // 2*pi/255

typedef __attribute__((ext_vector_type(8))) _Float16 f16x8;
typedef __attribute__((ext_vector_type(4))) float f32x4;

// ---------------- mirror + fc0 lift (+ identity BN slot init) --------------
__global__ void __launch_bounds__(256) k_fc0(
    const float* __restrict__ x, const float* __restrict__ w,
    const float* __restrict__ bias, _Float16* __restrict__ h,
    float* __restrict__ bnp0){
  int y = blockIdx.x, b = blockIdx.y, xx = threadIdx.x;
  if (blockIdx.x == 0 && blockIdx.y == 0 && xx < CH){
    bnp0[xx] = 1.f; bnp0[CH+xx] = 0.f;
  }
  size_t base = (size_t)(b*CH*HH + y)*RST + xx;
  if (xx >= HH){                      // pad column -> zero
    for (int d=0; d<CH; d++) h[base + (size_t)d*CST] = (_Float16)0.f;
    return;
  }
  int iy = (y  >= SS-1) ? y  - (SS-1) : (SS-1) - y;
  int ix = (xx >= SS-1) ? xx - (SS-1) : (SS-1) - xx;
  float sgn = ((y >= SS-1) == (xx >= SS-1)) ? 1.f : -1.f;
  float v0 = sgn * x[((b*DC + 0)*SS + iy)*SS + ix];
  float v1 = sgn * x[((b*DC + 1)*SS + iy)*SS + ix];
  float v2 = sgn * x[((b*DC + 2)*SS + iy)*SS + ix];
  for (int d=0; d<CH; d++){
    float v = bias[d] + v0*w[d] + v1*w[CH+d] + v2*w[2*CH+d];
    h[base + (size_t)d*CST] = (_Float16)v;
  }
}

// ------- DFT weight fragments for k_dftw (B-fragment order, f16 hi/lo) -----
__global__ void __launch_bounds__(256) k_wgen(
    _Float16* __restrict__ Whi, _Float16* __restrict__ Wlo){
  int t = blockIdx.x*256 + threadIdx.x;
  if (t >= 2*8*64) return;
  int ct = t >> 9, ks = (t >> 6) & 7, lane = t & 63;
  int col = ct*16 + (lane & 15);
  int kb = ks*32 + (lane >> 4)*8;
  for (int j=0; j<8; j++){
    int k = kb + j;
    float w = 0.f;
    if (k < 255 && col < 24){
      int m = col >> 1;
      float ang = TWOPI_N * (float)((k*m) % 255);
      w = (col & 1) ? -sinf(ang) : cosf(ang);
    }
    _Float16 hi = (_Float16)w;
    Whi[t*8+j] = hi;
    Wlo[t*8+j] = (_Float16)(w - (float)hi);
  }
}

// ------- inverse-W twiddle table for k_fuse (B-fragment order, f16 hi/lo) --
__global__ void __launch_bounds__(256) k_tgen(
    _Float16* __restrict__ Th, _Float16* __restrict__ Tl){
  int t = blockIdx.x*256 + threadIdx.x;
  if (t >= 16*64) return;
  int ct = t >> 6, lane = t & 63;
  int xx = ct*16 + (lane & 15);
  int jbase = (lane >> 4)*8;
  for (int j=0; j<8; j++){
    int jg = jbase + j;
    float v = 0.f;
    if (xx < HH && jg <= 22){
      if (jg == 0) v = 1.f;
      else if (jg & 1){ int kx=(jg+1)>>1; v =  cosf(TWOPI_N*(float)((kx*xx)%255)); }
      else            { int kx= jg>>1;    v = -sinf(TWOPI_N*(float)((kx*xx)%255)); }
    }
    _Float16 hi = (_Float16)v;
    Th[t*8+j] = hi;
    Tl[t*8+j] = (_Float16)(v - (float)hi);
  }
}

// ------- fc1 weight fragments (B-fragment order, f16 hi/lo) ----------------
__global__ void __launch_bounds__(256) k_w1gen(
    const float* __restrict__ w1, _Float16* __restrict__ W1h,
    _Float16* __restrict__ W1l){
  int t = blockIdx.x*256 + threadIdx.x;
  if (t >= 8*64) return;
  int nt = t >> 6, lane = t & 63;
  int col = nt*16 + (lane & 15);
  int kb = (lane >> 4)*8;
  for (int j=0; j<8; j++){
    float v = w1[(kb+j)*128 + col];
    _Float16 hi = (_Float16)v;
    W1h[t*8+j] = hi;
    W1l[t*8+j] = (_Float16)(v - (float)hi);
  }
}

// ---------------- forward DFT along W via f16 MFMA (packed-f16 BN) ---------
__global__ void __launch_bounds__(256) k_dftw(
    const _Float16* __restrict__ h, float* __restrict__ R,
    const _Float16* __restrict__ Whi, const _Float16* __restrict__ Wlo,
    const float* __restrict__ bnp, int relu){
  int t = threadIdx.x;
  int wid = t >> 6, lane = t & 63;
  int r0 = blockIdx.x*64 + wid*16;
  int rowg = r0 + (lane & 15);
  int c = (rowg / HH) & (CH-1);
  _Float16 sch = (_Float16)bnp[c], shh = (_Float16)bnp[CH+c];
  f16x8 scv, shv;
  #pragma unroll
  for (int u=0; u<8; u++){ scv[u]=sch; shv[u]=shh; }
  const _Float16* rp = h + (size_t)rowg*RST;
  int koff = (lane >> 4)*8;
  f32x4 acc0 = {0.f,0.f,0.f,0.f};
  f32x4 acc1 = {0.f,0.f,0.f,0.f};
  for (int ks=0; ks<8; ks++){
    int k0 = ks*32 + koff;
    f16x8 av = *(const f16x8*)(rp + k0);    // 16B aligned (RST=256)
    f16x8 a = av*scv + shv;                 // packed f16 BN
    if (relu){
      #pragma unroll
      for (int u=0; u<8; u++) a[u] = (a[u] > (_Float16)0.f) ? a[u] : (_Float16)0.f;
    }
    f16x8 b0h = *(const f16x8*)(Whi + ((size_t)(0*8+ks)*64 + lane)*8);
    f16x8 b0l = *(const f16x8*)(Wlo + ((size_t)(0*8+ks)*64 + lane)*8);
    f16x8 b1h = *(const f16x8*)(Whi + ((size_t)(1*8+ks)*64 + lane)*8);
    f16x8 b1l = *(const f16x8*)(Wlo + ((size_t)(1*8+ks)*64 + lane)*8);
    acc0 = __builtin_amdgcn_mfma_f32_16x16x32_f16(a, b0h, acc0, 0,0,0);
    acc0 = __builtin_amdgcn_mfma_f32_16x16x32_f16(a, b0l, acc0, 0,0,0);
    acc1 = __builtin_amdgcn_mfma_f32_16x16x32_f16(a, b1h, acc1, 0,0,0);
    acc1 = __builtin_amdgcn_mfma_f32_16x16x32_f16(a, b1l, acc1, 0,0,0);
  }
  int colq = lane & 15;
  int rq = r0 + (lane >> 4)*4;
  #pragma unroll
  for (int q=0; q<4; q++)
    R[(size_t)(rq+q)*24 + colq] = acc0[q];
  if (colq < 8){
    #pragma unroll
    for (int q=0; q<4; q++)
      R[(size_t)(rq+q)*24 + 16 + colq] = acc1[q];
  }
}

// ---------------- forward DFT along H: R -> Xf[bc][ky24][kx12], *1/255 -----
__global__ void __launch_bounds__(320) k_dfth(
    const float* __restrict__ R, float* __restrict__ Xf){
  __shared__ float lr[HH][M2][2];
  int t = threadIdx.x, bc = blockIdx.x;
  const float4* src = (const float4*)(R + bc*(HH*M2*2));
  for (int i=t; i<(HH*M2*2)/4; i+=320) ((float4*)lr)[i] = src[i];
  __syncthreads();
  if (t < KY24*M2){
    int ky = t / M2, kx = t - (t/M2)*M2;
    int freq = (ky < M1) ? ky : (HH - KY24 + ky);  // 0..11 or 243..254
    float ang = TWOPI_N * (float)freq;
    float c1 = cosf(ang), s1 = sinf(ang);
    float cr=1.f, sr=0.f, ar=0.f, ai=0.f;
    for (int y=0; y<HH; y++){
      float rr = lr[y][kx][0], ri = lr[y][kx][1];
      ar += rr*cr + ri*sr;   // * e^{-i theta}
      ai += ri*cr - rr*sr;
      float cn = cr*c1 - sr*s1;
      sr = sr*c1 + cr*s1;
      cr = cn;
    }
    const float inv = 1.0f/255.0f;
    int o = (bc*KY24 + ky)*(M2*2) + kx*2;
    Xf[o]   = ar*inv;
    Xf[o+1] = ai*inv;
  }
}

// ---------------- per-mode 32x32 complex channel mix -----------------------
__global__ void __launch_bounds__(384) k_mix(
    const float* __restrict__ Xf, const float* __restrict__ w,
    float* __restrict__ Y){
  int m2 = blockIdx.x, blk = blockIdx.y, b = blockIdx.z;
  int t = threadIdx.x;
  __shared__ float lx[CH][M1][2];
  for (int i=t; i<CH*M1*2; i+=384){
    int ii = i/(M1*2), rem = i - ii*(M1*2);
    int m1 = rem>>1, comp = rem&1;
    lx[ii][m1][comp] = Xf[((b*CH+ii)*KY24 + blk*M1 + m1)*(M2*2) + m2*2 + comp];
  }
  __syncthreads();
  int m1 = t >> 5, o = t & 31;
  float ar=0.f, ai=0.f;
  const float* wp = w + ((blk*CH*CH + o)*M1 + m1)*(M2*2) + m2*2;
  const int istride = CH*M1*M2*2;
  for (int i=0;i<CH;i++){
    float xr = lx[i][m1][0], xi = lx[i][m1][1];
    float wr = wp[0], wi = wp[1];
    ar += xr*wr - xi*wi;
    ai += xr*wi + xi*wr;
    wp += istride;
  }
  int oidx = ((b*CH+o)*KY24 + blk*M1 + m1)*(M2*2) + m2*2;
  Y[oidx]   = ar;
  Y[oidx+1] = ai;
}

// ---------------- inverse along H: Y modes -> G[bo][y][kx] -----------------
__global__ void __launch_bounds__(256) k_idfth(
    const float* __restrict__ Y, float* __restrict__ G){
  __shared__ float ly[KY24][M2][2];
  int t = threadIdx.x, bo = blockIdx.x;
  const float4* src = (const float4*)(Y + bo*(KY24*M2*2));
  for (int i=t; i<(KY24*M2*2)/4; i+=256) ((float4*)ly)[i] = src[i];
  __syncthreads();
  const float inv = 1.0f/255.0f;
  for (int p=t; p<HH*M2; p+=256){
    int y = p/M2, kx = p - (p/M2)*M2;
    float ang = TWOPI_N * (float)y;
    float c1 = cosf(ang), s1 = sinf(ang);
    float ar = ly[0][kx][0], ai = ly[0][kx][1];
    float c = c1, s = s1;
    #pragma unroll
    for (int k=1; k<=11; k++){
      float yr = ly[k][kx][0],     yi = ly[k][kx][1];
      ar += yr*c - yi*s;                 // * T_k
      ai += yr*s + yi*c;
      float zr = ly[24-k][kx][0],  zi = ly[24-k][kx][1];
      ar += zr*c + zi*s;                 // * conj(T_k)
      ai += zi*c - zr*s;
      float cn = c*c1 - s*s1;
      s = s*c1 + c*s1;
      c = cn;
    }
    {
      float zr = ly[12][kx][0], zi = ly[12][kx][1];   // freq -12: conj(T_12)
      ar += zr*c + zi*s;
      ai += zi*c - zr*s;
    }
    float f = (kx==0) ? inv : 2.0f*inv;
    int o = (bo*HH + y)*(M2*2) + kx*2;
    G[o]   = ar*f;
    G[o+1] = ai*f;
  }
}

// ------- fused MFMA: BN+ReLU-on-load + 1x1 conv + inverse-W + BN partials --
// stage: coalesced f16x8 loads + packed-f16 BN; B-fragments in LDS (ct pad 65)
// epilogue: acc -> LDS transpose -> coalesced f16x8 row stores
__global__ void __launch_bounds__(256) k_fuse(
    const _Float16* __restrict__ h, const float* __restrict__ G,
    const float* __restrict__ cw, const float* __restrict__ cb,
    _Float16* __restrict__ tout, float* __restrict__ partials,
    const _Float16* __restrict__ Th, const _Float16* __restrict__ Tl,
    const float* __restrict__ bnp, int relu){
  __shared__ _Float16 buf[8448];   // Bf view: (ct*65+lane)*8+j ; Of view: o*264+xx
  __shared__ float red[CH][4][2];
  int y = blockIdx.x, b = blockIdx.y, t = threadIdx.x;
  size_t hbase = (size_t)(b*CH*HH + y)*RST;
  // --- stage: 4 x f16x8 coalesced loads, packed BN, fragment-scatter to LDS ---
  #pragma unroll
  for (int it=0; it<4; it++){
    int idx = it*256 + t;
    int c = idx >> 5, xg = idx & 31;
    f16x8 av = *(const f16x8*)(h + hbase + (size_t)c*CST + xg*8);
    _Float16 sch = (_Float16)bnp[c], shh = (_Float16)bnp[CH+c];
    f16x8 scv, shv;
    #pragma unroll
    for (int u=0; u<8; u++){ scv[u]=sch; shv[u]=shh; }
    f16x8 z = av*scv + shv;
    if (relu){
      #pragma unroll
      for (int u=0; u<8; u++) z[u] = (z[u] > (_Float16)0.f) ? z[u] : (_Float16)0.f;
    }
    int base = ((xg>>1)*65 + ((xg&1)*8) + ((c>>3)<<4))*8 + (c&7);
    #pragma unroll
    for (int u=0; u<8; u++) buf[base + u*8] = z[u];
  }
  // --- A fragments: conv weights (split hi/lo) + spectral G row (single) ---
  int w = t >> 6, lane = t & 63;
  int arow = lane & 15, koff = (lane >> 4)*8;
  f16x8 a0h[2], a0l[2], a1[2];
  #pragma unroll
  for (int rt=0; rt<2; rt++){
    int o = rt*16 + arow;
    #pragma unroll
    for (int j=0; j<8; j++){
      float v = cw[o*CH + koff + j];
      _Float16 hi = (_Float16)v;
      a0h[rt][j] = hi;
      a0l[rt][j] = (_Float16)(v - (float)hi);
    }
    const float* gp = G + ((size_t)(b*CH+o)*HH + y)*24;
    #pragma unroll
    for (int j=0; j<8; j++){
      int jg = koff + j;                 // jg>=23: T rows are zero -> don't care
      float v = (jg==0) ? gp[0] : gp[jg+1];
      a1[rt][j] = (_Float16)v;
    }
  }
  __syncthreads();
  // --- MFMA: each wave owns 4 col-tiles (64 xx), all 32 output rows ---
  f32x4 acc[2][4];
  #pragma unroll
  for (int rt=0; rt<2; rt++)
    #pragma unroll
    for (int cl=0; cl<4; cl++) acc[rt][cl] = (f32x4){0.f,0.f,0.f,0.f};
  #pragma unroll
  for (int cl=0; cl<4; cl++){
    int ct = w*4 + cl;
    f16x8 bd = *(const f16x8*)(buf + ((size_t)ct*65 + lane)*8);
    f16x8 th = *(const f16x8*)(Th + ((size_t)ct*64 + lane)*8);
    f16x8 tl = *(const f16x8*)(Tl + ((size_t)ct*64 + lane)*8);
    #pragma unroll
    for (int rt=0; rt<2; rt++){
      acc[rt][cl] = __builtin_amdgcn_mfma_f32_16x16x32_f16(a0h[rt], bd, acc[rt][cl], 0,0,0);
      acc[rt][cl] = __builtin_amdgcn_mfma_f32_16x16x32_f16(a0l[rt], bd, acc[rt][cl], 0,0,0);
      acc[rt][cl] = __builtin_amdgcn_mfma_f32_16x16x32_f16(a1[rt], th, acc[rt][cl], 0,0,0);
      acc[rt][cl] = __builtin_amdgcn_mfma_f32_16x16x32_f16(a1[rt], tl, acc[rt][cl], 0,0,0);
    }
  }
  // --- BN partial sums from registers (exclude pad col) ---
  float s1[2][4], s2[2][4];
  #pragma unroll
  for (int rt=0; rt<2; rt++)
    #pragma unroll
    for (int q=0; q<4; q++){ s1[rt][q]=0.f; s2[rt][q]=0.f; }
  #pragma unroll
  for (int rt=0; rt<2; rt++)
    #pragma unroll
    for (int cl=0; cl<4; cl++){
      int xxo = (w*4 + cl)*16 + (lane & 15);
      bool ok = xxo < HH;
      #pragma unroll
      for (int q=0; q<4; q++){
        int o = rt*16 + (lane >> 4)*4 + q;
        float v = acc[rt][cl][q] + cb[o];
        float vv = ok ? v : 0.f;
        s1[rt][q] += vv;
        s2[rt][q] += vv*vv;
      }
    }
  #pragma unroll
  for (int rt=0; rt<2; rt++)
    #pragma unroll
    for (int q=0; q<4; q++){
      float v1 = s1[rt][q], v2 = s2[rt][q];
      #pragma unroll
      for (int off=8; off>0; off>>=1){
        v1 += __shfl_xor(v1, off, 16);
        v2 += __shfl_xor(v2, off, 16);
      }
      if ((lane & 15) == 0){
        int o = rt*16 + (lane >> 4)*4 + q;
        red[o][w][0] = v1;
        red[o][w][1] = v2;
      }
    }
  __syncthreads();      // all Bf reads done -> safe to overwrite buf as Of
  #pragma unroll
  for (int rt=0; rt<2; rt++)
    #pragma unroll
    for (int cl=0; cl<4; cl++){
      int xxo = (w*4 + cl)*16 + (lane & 15);
      #pragma unroll
      for (int q=0; q<4; q++){
        int o = rt*16 + (lane >> 4)*4 + q;       // C/D layout (m89)
        buf[o*264 + xxo] = (_Float16)(acc[rt][cl][q] + cb[o]);
      }
    }
  __syncthreads();
  // --- coalesced f16x8 row stores (pad col written too; harmless) ---
  {
    int o = t >> 3, xb = (t & 7)*32;
    #pragma unroll
    for (int v4=0; v4<4; v4++){
      f16x8 vv = *(const f16x8*)(buf + o*264 + xb + v4*8);
      *(f16x8*)(tout + hbase + (size_t)o*CST + xb + v4*8) = vv;
    }
  }
  if (t < CH*2){
    int oo = t >> 1, st = t & 1;
    float s = red[oo][0][st] + red[oo][1][st] + red[oo][2][st] + red[oo][3][st];
    partials[(oo*2+st)*(BATCH*HH) + b*HH + y] = s;
  }
}

// ---------------- deterministic stats reduce -> scale/shift ----------------
__global__ void __launch_bounds__(256) k_stats(
    const float* __restrict__ partials,
    const float* __restrict__ g, const float* __restrict__ bb,
    float* __restrict__ bnp){
  __shared__ float acc[256];
  int o = blockIdx.x, t = threadIdx.x;
  int half = t >> 7, j = t & 127;
  const float* p = partials + (size_t)(o*2+half)*(BATCH*HH);
  float s = 0.f;
  for (int k=j; k<BATCH*HH; k+=128) s += p[k];
  acc[t] = s;
  __syncthreads();
  for (int w2=64; w2>0; w2>>=1){
    if (j < w2) acc[t] += acc[t+w2];
    __syncthreads();
  }
  if (t == 0){
    const float N = (float)BATCH * (float)(HH*HH);
    float mean = acc[0] / N;
    float var  = acc[128] / N - mean*mean;
    float iv = rsqrtf(var + 1e-5f);
    float scv = g[o]*iv;
    bnp[o]      = scv;
    bnp[CH + o] = bb[o] - mean*scv;
  }
}

// ------- final MFMA: BN(l3) + fc1 + relu + fc2, quadrant only --------------
__global__ void __launch_bounds__(256) k_final(
    const _Float16* __restrict__ tb, const float* __restrict__ bnp,
    const _Float16* __restrict__ W1h, const _Float16* __restrict__ W1l,
    const float* __restrict__ b1, const float* __restrict__ w2,
    const float* __restrict__ b2, float* __restrict__ out){
  __shared__ _Float16 Vf[128][40];      // pixel-major, 80B row stride
  int yq = blockIdx.x, b = blockIdx.y, t = threadIdx.x;
  int y = (SS-1) + yq;
  for (int i=t; i<CH*SS; i+=256){
    int c = i >> 7, xx = i & 127;
    float v = (float)tb[((size_t)(b*CH + c)*HH + y)*RST + (SS-1) + xx]
              * bnp[c] + bnp[CH+c];
    Vf[xx][c] = (_Float16)v;
  }
  __syncthreads();
  int w = t >> 6, lane = t & 63;
  int prow = lane & 15, koff = (lane >> 4)*8, col = lane & 15;
  f16x8 a0 = *(const f16x8*)&Vf[w*32 + prow][koff];
  f16x8 a1 = *(const f16x8*)&Vf[w*32 + 16 + prow][koff];
  float s0[4] = {0.f,0.f,0.f,0.f}, s1[4] = {0.f,0.f,0.f,0.f};
  #pragma unroll
  for (int nt=0; nt<8; nt++){
    f16x8 bh = *(const f16x8*)(W1h + ((size_t)nt*64 + lane)*8);
    f16x8 bl = *(const f16x8*)(W1l + ((size_t)nt*64 + lane)*8);
    f32x4 acc0 = {0.f,0.f,0.f,0.f}, acc1 = {0.f,0.f,0.f,0.f};
    acc0 = __builtin_amdgcn_mfma_f32_16x16x32_f16(a0, bh, acc0, 0,0,0);
    acc0 = __builtin_amdgcn_mfma_f32_16x16x32_f16(a0, bl, acc0, 0,0,0);
    acc1 = __builtin_amdgcn_mfma_f32_16x16x32_f16(a1, bh, acc1, 0,0,0);
    acc1 = __builtin_amdgcn_mfma_f32_16x16x32_f16(a1, bl, acc1, 0,0,0);
    float b1v = b1[nt*16 + col];
    float w2v = w2[nt*16 + col];
    #pragma unroll
    for (int q=0; q<4; q++){
      s0[q] += fmaxf(acc0[q] + b1v, 0.f)*w2v;
      s1[q] += fmaxf(acc1[q] + b1v, 0.f)*w2v;
    }
  }
  float o2b = b2[0];
  #pragma unroll
  for (int q=0; q<4; q++){
    float v0 = s0[q], v1 = s1[q];
    #pragma unroll
    for (int off=8; off>0; off>>=1){
      v0 += __shfl_xor(v0, off, 16);
      v1 += __shfl_xor(v1, off, 16);
    }
    if (col == (unsigned)q){           // one writer per pixel, deterministic
      int p0 = w*32 + (lane >> 4)*4 + q;
      int p1 = p0 + 16;
      float r0 = v0 + o2b, r1 = v1 + o2b;
      int ob = (b*DC)*SS*SS + yq*SS;
      #pragma unroll
      for (int cc=0; cc<DC; cc++){
        out[ob + cc*SS*SS + p0] = r0;
        out[ob + cc*SS*SS + p1] = r1;
      }
    }
  }
}

extern "C" void kernel_launch(void* const* d_in, const int* in_sizes, int n_in,
                              void* d_out, int out_size, void* d_ws, size_t ws_size,
                              hipStream_t stream) {
  (void)in_sizes; (void)n_in; (void)out_size; (void)ws_size;
  const float* x      = (const float*)d_in[0];
  const float* fc0_w  = (const float*)d_in[1];
  const float* fc0_b  = (const float*)d_in[2];
  const float* spec_w = (const float*)d_in[3];
  const float* conv_w = (const float*)d_in[4];
  const float* conv_b = (const float*)d_in[5];
  const float* bn_g   = (const float*)d_in[6];
  const float* bn_b   = (const float*)d_in[7];
  const float* fc1_w  = (const float*)d_in[8];
  const float* fc1_b  = (const float*)d_in[9];
  const float* fc2_w  = (const float*)d_in[10];
  const float* fc2_b  = (const float*)d_in[11];
  float* out = (float*)d_out;
  float* ws  = (float*)d_ws;

  // field: 16*32*255*256 f16 = 33,423,360 halves = 16,711,680 floats (~64 MiB)
  _Float16* field = (_Float16*)ws;
  float* Rbuf  = ws + 16711680;                        // NROWS*24 = 3,133,440
  float* Xf    = Rbuf + (size_t)NROWS*24;              // 294,912
  float* Yb    = Xf   + (size_t)BATCH*CH*KY24*M2*2;    // 294,912
  float* parts = Yb   + (size_t)BATCH*CH*KY24*M2*2;    // 261,120
  float* bnp   = parts + (size_t)64*BATCH*HH;          // 5 slots x 64
  _Float16* Whi = (_Float16*)(bnp + 5*64);             // 8192 halves each
  _Float16* Wlo = Whi + 2*8*64*8;
  _Float16* Th  = Wlo + 2*8*64*8;
  _Float16* Tl  = Th  + 16*64*8;
  _Float16* W1h = Tl  + 16*64*8;                       // 4096 halves each
  _Float16* W1l = W1h + 8*64*8;

  k_wgen<<<4, 256, 0, stream>>>(Whi, Wlo);
  k_tgen<<<4, 256, 0, stream>>>(Th, Tl);
  k_w1gen<<<2, 256, 0, stream>>>(fc1_w, W1h, W1l);
  k_fc0<<<dim3(HH, BATCH), 256, 0, stream>>>(x, fc0_w, fc0_b, field, bnp);

  const size_t wstride = (size_t)2*CH*CH*M1*M2*2;      // per-layer spec_w elems
  for (int l=0; l<4; l++){
    const float* bnin = bnp + (size_t)l*64;            // BN of layer l-1 (or id)
    int relu = (l >= 1);                               // ReLU after layers 0..2
    k_dftw <<<NROWS/64, 256, 0, stream>>>(field, Rbuf, Whi, Wlo, bnin, relu);
    k_dfth <<<BATCH*CH, 320, 0, stream>>>(Rbuf, Xf);
    k_mix  <<<dim3(M2, 2, BATCH), 384, 0, stream>>>(Xf, spec_w + (size_t)l*wstride, Yb);
    k_idfth<<<BATCH*CH, 256, 0, stream>>>(Yb, Rbuf);
    k_fuse <<<dim3(HH, BATCH), 256, 0, stream>>>(field, Rbuf, conv_w + l*CH*CH,
                                                 conv_b + l*CH, field, parts,
                                                 Th, Tl, bnin, relu);
    k_stats<<<CH, 256, 0, stream>>>(parts, bn_g + l*CH, bn_b + l*CH,
                                    bnp + (size_t)(l+1)*64);
  }
  k_final<<<dim3(SS, BATCH), 256, 0, stream>>>(field, bnp + 4*64, W1h, W1l,
                                               fc1_b, fc2_w, fc2_b, out);
}